// Round 1
// baseline (42416.342 us; speedup 1.0000x reference)
//
#include <hip/hip_runtime.h>
#include <stdint.h>

#define VOCAB 50257
#define B 256
#define EMB 300
#define HID 700
#define G3 2100          // 3*HID
#define ZDIM 500
#define ATTR_EMBD 200
#define MAXLEN 30
#define SEQ 31           // MAXLEN+1
#define HY_ELEMS (B*SEQ*HID)

// ---------------- threefry2x32 (JAX-exact, 20 rounds) ----------------
__device__ __forceinline__ uint32_t rotl32(uint32_t x, int r) {
  return (x << r) | (x >> (32 - r));
}

__device__ __forceinline__ void threefry2x32(uint32_t k0, uint32_t k1,
                                             uint32_t x0, uint32_t x1,
                                             uint32_t& o0, uint32_t& o1) {
  const uint32_t ks2 = k0 ^ k1 ^ 0x1BD11BDAu;
  x0 += k0; x1 += k1;
#define TF_R4(a, b, c, d)                                     \
  x0 += x1; x1 = rotl32(x1, a); x1 ^= x0;                     \
  x0 += x1; x1 = rotl32(x1, b); x1 ^= x0;                     \
  x0 += x1; x1 = rotl32(x1, c); x1 ^= x0;                     \
  x0 += x1; x1 = rotl32(x1, d); x1 ^= x0;
  TF_R4(13, 15, 26, 6)  x0 += k1;  x1 += ks2 + 1u;
  TF_R4(17, 29, 16, 24) x0 += ks2; x1 += k0 + 2u;
  TF_R4(13, 15, 26, 6)  x0 += k0;  x1 += k1 + 3u;
  TF_R4(17, 29, 16, 24) x0 += k1;  x1 += ks2 + 4u;
  TF_R4(13, 15, 26, 6)  x0 += ks2; x1 += k0 + 5u;
#undef TF_R4
  o0 = x0; o1 = x1;
}

// ---------------- init: h0, step keys, slot zero, token rows, y[:,30] ----------------
__global__ void k_init(const float* __restrict__ z, const int* __restrict__ l,
                       const float* __restrict__ attr_w,
                       float* __restrict__ hbuf0, uint32_t* __restrict__ keys,
                       unsigned long long* __restrict__ slots,
                       int* __restrict__ tok, float* __restrict__ y_out) {
  int idx = blockIdx.x * blockDim.x + threadIdx.x;
  if (idx < B * HID) {
    int b = idx / HID, i = idx % HID;
    float v = (i < ZDIM) ? z[b * ZDIM + i]
                         : attr_w[l[b] * ATTR_EMBD + (i - ZDIM)];
    hbuf0[idx] = v;
  }
  if (idx < MAXLEN) {
    // partitionable threefry split: subkey_t = threefry(key=(0,42), (0, t))
    uint32_t o0, o1;
    threefry2x32(0u, 42u, 0u, (uint32_t)idx, o0, o1);
    keys[2 * idx] = o0; keys[2 * idx + 1] = o1;
  }
  if (idx < MAXLEN * B) slots[idx] = 0ull;  // must re-zero every call (ws poisoned)
  if (idx < B) {
    tok[idx] = 1;             // row 0: SOS
    tok[31 * B + idx] = 2;    // row 31: EOS (used by final forced step)
    y_out[idx * SEQ + MAXLEN] = 2.0f;  // y[:,30] = EOS
  }
}

// ---------------- gates GEMM: gi = x@W_ih.T  /  gh = h@W_hh.T (blockIdx.z) ----------------
// tile 32j x 32b, 256 threads, 2x2 micro-tile, Kt=20 (300=15*20, 700=35*20)
__global__ void k_gates(const float* __restrict__ W_ih, const float* __restrict__ W_hh,
                        const float* __restrict__ emb_w, const float* __restrict__ hprev,
                        const int* __restrict__ tok,
                        float* __restrict__ gi, float* __restrict__ gh) {
  const int zz = blockIdx.z;
  const float* __restrict__ W = zz ? W_hh : W_ih;
  const int K = zz ? HID : EMB;
  float* __restrict__ out = zz ? gh : gi;
  __shared__ float w_lds[20][32];
  __shared__ float xh_lds[20][32];
  const int jbase = blockIdx.x * 32;
  const int bbase = blockIdx.y * 32;
  const int tid = threadIdx.x;
  const int tj = tid % 16, tb = tid / 16;
  float a00 = 0.f, a01 = 0.f, a10 = 0.f, a11 = 0.f;
  for (int k0 = 0; k0 < K; k0 += 20) {
    for (int idx = tid; idx < 640; idx += 256) {
      int col = idx / 20, kk = idx % 20;
      int j = jbase + col;
      w_lds[kk][col] = (j < G3) ? W[j * K + k0 + kk] : 0.0f;
      int b = bbase + col;
      float xv;
      if (zz) xv = hprev[b * HID + k0 + kk];
      else    xv = emb_w[tok[b] * EMB + k0 + kk];
      xh_lds[kk][col] = xv;
    }
    __syncthreads();
#pragma unroll
    for (int kk = 0; kk < 20; ++kk) {
      float w0 = w_lds[kk][tj * 2], w1 = w_lds[kk][tj * 2 + 1];
      float h0 = xh_lds[kk][tb * 2], h1 = xh_lds[kk][tb * 2 + 1];
      a00 += w0 * h0; a01 += w0 * h1;
      a10 += w1 * h0; a11 += w1 * h1;
    }
    __syncthreads();
  }
  int j0 = jbase + tj * 2, b0 = bbase + tb * 2;
  if (j0 < G3)     { out[b0 * G3 + j0] = a00;     out[(b0 + 1) * G3 + j0] = a01; }
  if (j0 + 1 < G3) { out[b0 * G3 + j0 + 1] = a10; out[(b0 + 1) * G3 + j0 + 1] = a11; }
}

// ---------------- pointwise GRU update ----------------
__global__ void k_hnew(const float* __restrict__ gi, const float* __restrict__ gh,
                       const float* __restrict__ b_ih, const float* __restrict__ b_hh,
                       const float* __restrict__ hprev, float* __restrict__ hnext,
                       float* __restrict__ hy, int t) {
  int idx = blockIdx.x * blockDim.x + threadIdx.x;
  if (idx >= B * HID) return;
  int b = idx / HID, i = idx % HID;
  float ir = gi[b * G3 + i]           + b_ih[i];
  float iz = gi[b * G3 + HID + i]     + b_ih[HID + i];
  float in_ = gi[b * G3 + 2 * HID + i] + b_ih[2 * HID + i];
  float hr = gh[b * G3 + i]           + b_hh[i];
  float hz = gh[b * G3 + HID + i]     + b_hh[HID + i];
  float hn = gh[b * G3 + 2 * HID + i] + b_hh[2 * HID + i];
  float r  = 1.0f / (1.0f + expf(-(ir + hr)));
  float zg = 1.0f / (1.0f + expf(-(iz + hz)));
  float n  = tanhf(in_ + r * hn);
  float h  = (1.0f - zg) * n + zg * hprev[idx];
  hnext[idx] = h;
  hy[(size_t)b * SEQ * HID + (size_t)t * HID + i] = h;
}

// ---------------- logits GEMM + gumbel + argmax (fused) ----------------
// tile 64v x 256b, 256 threads, 8x8 micro-tile, Kt=20 (700=35*20)
__global__ void k_logits(const float* __restrict__ h, const float* __restrict__ out_w,
                         const float* __restrict__ out_b, const uint32_t* __restrict__ keys,
                         unsigned long long* __restrict__ slot, int t) {
  __shared__ float w_lds[20][64];
  __shared__ float h_lds[20][256];
  const int vbase = blockIdx.x * 64;
  const int tid = threadIdx.x;
  const int tv = tid % 8, tb = tid / 8;  // v = vbase+tv*8+iv ; b = tb*8+ib
  float acc[8][8];
#pragma unroll
  for (int i = 0; i < 8; ++i)
#pragma unroll
    for (int j = 0; j < 8; ++j) acc[i][j] = 0.f;

  for (int k0 = 0; k0 < HID; k0 += 20) {
    for (int idx = tid; idx < 64 * 20; idx += 256) {
      int vv = idx / 20, kk = idx % 20;
      int v = vbase + vv;
      w_lds[kk][vv] = (v < VOCAB) ? out_w[(size_t)v * HID + k0 + kk] : 0.0f;
    }
    for (int idx = tid; idx < 256 * 20; idx += 256) {
      int bb = idx / 20, kk = idx % 20;
      h_lds[kk][bb] = h[bb * HID + k0 + kk];
    }
    __syncthreads();
#pragma unroll
    for (int kk = 0; kk < 20; ++kk) {
      float wv[8], hv[8];
      *(float4*)&wv[0] = *(const float4*)&w_lds[kk][tv * 8];
      *(float4*)&wv[4] = *(const float4*)&w_lds[kk][tv * 8 + 4];
      *(float4*)&hv[0] = *(const float4*)&h_lds[kk][tb * 8];
      *(float4*)&hv[4] = *(const float4*)&h_lds[kk][tb * 8 + 4];
#pragma unroll
      for (int iv = 0; iv < 8; ++iv)
#pragma unroll
        for (int ib = 0; ib < 8; ++ib) acc[iv][ib] += wv[iv] * hv[ib];
    }
    __syncthreads();
  }

  const uint32_t key0 = keys[2 * t], key1 = keys[2 * t + 1];
  for (int ib = 0; ib < 8; ++ib) {
    const int b = tb * 8 + ib;
    unsigned long long best = 0ull;
#pragma unroll
    for (int iv = 0; iv < 8; ++iv) {
      int v = vbase + tv * 8 + iv;
      if (v >= VOCAB) continue;
      float s = acc[iv][ib] + out_b[v];
      // JAX partitionable random_bits: bits = o0 ^ o1 of threefry(key, (0, j))
      uint32_t j = (uint32_t)(b * VOCAB + v);
      uint32_t o0, o1;
      threefry2x32(key0, key1, 0u, j, o0, o1);
      uint32_t bits = o0 ^ o1;
      float f = __uint_as_float((bits >> 9) | 0x3f800000u) - 1.0f;
      float u = fmaxf(f, 1.17549435e-38f);
      float g = -logf(-logf(u));
      s += g;
      uint32_t us = __float_as_uint(s);
      us = (us & 0x80000000u) ? ~us : (us | 0x80000000u);
      unsigned long long cand =
          ((unsigned long long)us << 32) | (uint32_t)(~(uint32_t)v);  // first-index tie-break
      if (cand > best) best = cand;
    }
    // reduce across the 8 tv lanes (contiguous lanes within the wave)
#pragma unroll
    for (int off = 1; off < 8; off <<= 1) {
      unsigned long long other = __shfl_xor(best, off, 64);
      if (other > best) best = other;
    }
    if (tv == 0) atomicMax(&slot[b], best);
  }
}

// ---------------- token extraction ----------------
__global__ void k_tok(const unsigned long long* __restrict__ slot,
                      int* __restrict__ tok_next, float* __restrict__ y_out, int t) {
  int b = threadIdx.x;
  unsigned long long p = slot[b];
  uint32_t v = ~((uint32_t)(p & 0xFFFFFFFFull));
  tok_next[b] = (int)v;
  y_out[b * SEQ + t] = (float)v;
}

// ---------------- host launch ----------------
extern "C" void kernel_launch(void* const* d_in, const int* in_sizes, int n_in,
                              void* d_out, int out_size, void* d_ws, size_t ws_size,
                              hipStream_t stream) {
  const float* z      = (const float*)d_in[0];
  const int*   l      = (const int*)  d_in[1];
  const float* emb_w  = (const float*)d_in[2];
  const float* attr_w = (const float*)d_in[3];
  const float* W_ih   = (const float*)d_in[4];
  const float* W_hh   = (const float*)d_in[5];
  const float* b_ih   = (const float*)d_in[6];
  const float* b_hh   = (const float*)d_in[7];
  const float* out_w  = (const float*)d_in[8];
  const float* out_b  = (const float*)d_in[9];

  float* hy    = (float*)d_out;
  float* y_out = (float*)d_out + HY_ELEMS;

  char* ws = (char*)d_ws;
  uint32_t* keys            = (uint32_t*)ws;                         // 256 B
  unsigned long long* slots = (unsigned long long*)(ws + 256);       // 30*256*8 = 61440
  int* tokbuf               = (int*)(ws + 256 + 61440);              // 32*256*4 = 32768
  float* hbuf               = (float*)(ws + 256 + 61440 + 32768);    // 2*B*HID*4
  float* gi                 = hbuf + 2 * B * HID;                    // B*G3
  float* gh                 = gi + B * G3;                           // B*G3

  k_init<<<(B * HID + 255) / 256, 256, 0, stream>>>(z, l, attr_w, hbuf, keys, slots,
                                                    tokbuf, y_out);

  for (int t = 0; t <= MAXLEN; ++t) {
    float* hprev = hbuf + (t % 2) * B * HID;
    float* hnext = hbuf + ((t + 1) % 2) * B * HID;
    const int* tok_t = tokbuf + ((t == MAXLEN) ? 31 : t) * B;

    dim3 ggrid(66, 8, 2);
    k_gates<<<ggrid, 256, 0, stream>>>(W_ih, W_hh, emb_w, hprev, tok_t, gi, gh);
    k_hnew<<<(B * HID + 255) / 256, 256, 0, stream>>>(gi, gh, b_ih, b_hh, hprev,
                                                      hnext, hy, t);
    if (t < MAXLEN) {
      k_logits<<<(VOCAB + 63) / 64, 256, 0, stream>>>(hnext, out_w, out_b, keys,
                                                      slots + (size_t)t * B, t);
      k_tok<<<1, 256, 0, stream>>>(slots + (size_t)t * B, tokbuf + (t + 1) * B,
                                   y_out, t);
    }
  }
}

// Round 2
// 20131.456 us; speedup vs baseline: 2.1070x; 2.1070x over previous
//
#include <hip/hip_runtime.h>
#include <stdint.h>

#define VOCAB 50257
#define B 256
#define EMB 300
#define HID 700
#define G3 2100          // 3*HID
#define ZDIM 500
#define ATTR_EMBD 200
#define MAXLEN 30
#define SEQ 31           // MAXLEN+1
#define HY_ELEMS (B*SEQ*HID)

// ---------------- threefry2x32 (JAX-exact, 20 rounds) ----------------
__device__ __forceinline__ uint32_t rotl32(uint32_t x, int r) {
  return (x << r) | (x >> (32 - r));
}

__device__ __forceinline__ void threefry2x32(uint32_t k0, uint32_t k1,
                                             uint32_t x0, uint32_t x1,
                                             uint32_t& o0, uint32_t& o1) {
  const uint32_t ks2 = k0 ^ k1 ^ 0x1BD11BDAu;
  x0 += k0; x1 += k1;
#define TF_R4(a, b, c, d)                                     \
  x0 += x1; x1 = rotl32(x1, a); x1 ^= x0;                     \
  x0 += x1; x1 = rotl32(x1, b); x1 ^= x0;                     \
  x0 += x1; x1 = rotl32(x1, c); x1 ^= x0;                     \
  x0 += x1; x1 = rotl32(x1, d); x1 ^= x0;
  TF_R4(13, 15, 26, 6)  x0 += k1;  x1 += ks2 + 1u;
  TF_R4(17, 29, 16, 24) x0 += ks2; x1 += k0 + 2u;
  TF_R4(13, 15, 26, 6)  x0 += k0;  x1 += k1 + 3u;
  TF_R4(17, 29, 16, 24) x0 += k1;  x1 += ks2 + 4u;
  TF_R4(13, 15, 26, 6)  x0 += ks2; x1 += k0 + 5u;
#undef TF_R4
  o0 = x0; o1 = x1;
}

// ---------------- init: h0, step keys, slot zero, token rows, y[:,30] ----------------
__global__ void k_init(const float* __restrict__ z, const int* __restrict__ l,
                       const float* __restrict__ attr_w,
                       float* __restrict__ hbuf0, uint32_t* __restrict__ keys,
                       unsigned long long* __restrict__ slots,
                       int* __restrict__ tok, float* __restrict__ y_out) {
  int idx = blockIdx.x * blockDim.x + threadIdx.x;
  if (idx < B * HID) {
    int b = idx / HID, i = idx % HID;
    float v = (i < ZDIM) ? z[b * ZDIM + i]
                         : attr_w[l[b] * ATTR_EMBD + (i - ZDIM)];
    hbuf0[idx] = v;
  }
  if (idx < MAXLEN) {
    // partitionable threefry split: subkey_t = threefry(key=(0,42), (0, t))
    uint32_t o0, o1;
    threefry2x32(0u, 42u, 0u, (uint32_t)idx, o0, o1);
    keys[2 * idx] = o0; keys[2 * idx + 1] = o1;
  }
  if (idx < MAXLEN * B) slots[idx] = 0ull;  // must re-zero every call (ws poisoned)
  if (idx < B) {
    tok[idx] = 1;             // row 0: SOS
    tok[31 * B + idx] = 2;    // row 31: EOS (used by final forced step)
    y_out[idx * SEQ + MAXLEN] = 2.0f;  // y[:,30] = EOS
  }
}

// ---------------- gates GEMM: gi = x@W_ih.T  /  gh = h@W_hh.T (blockIdx.z) ----------------
// tile 32j x 32b, 256 threads, 2x2 micro-tile, Kt=20 (300=15*20, 700=35*20)
// LDS rows padded +4 dwords: bank = (4*kk + col) % 32 -> staging writes ~3-way
// instead of 20-way (stride-32 fixed-column writes all hit bank 0).
__global__ void k_gates(const float* __restrict__ W_ih, const float* __restrict__ W_hh,
                        const float* __restrict__ emb_w, const float* __restrict__ hprev,
                        const int* __restrict__ tok,
                        float* __restrict__ gi, float* __restrict__ gh) {
  const int zz = blockIdx.z;
  const float* __restrict__ W = zz ? W_hh : W_ih;
  const int K = zz ? HID : EMB;
  float* __restrict__ out = zz ? gh : gi;
  __shared__ float w_lds[20][36];
  __shared__ float xh_lds[20][36];
  const int jbase = blockIdx.x * 32;
  const int bbase = blockIdx.y * 32;
  const int tid = threadIdx.x;
  const int tj = tid % 16, tb = tid / 16;
  float a00 = 0.f, a01 = 0.f, a10 = 0.f, a11 = 0.f;
  for (int k0 = 0; k0 < K; k0 += 20) {
    for (int idx = tid; idx < 640; idx += 256) {
      int col = idx / 20, kk = idx % 20;
      int j = jbase + col;
      w_lds[kk][col] = (j < G3) ? W[j * K + k0 + kk] : 0.0f;
      int b = bbase + col;
      float xv;
      if (zz) xv = hprev[b * HID + k0 + kk];
      else    xv = emb_w[tok[b] * EMB + k0 + kk];
      xh_lds[kk][col] = xv;
    }
    __syncthreads();
#pragma unroll
    for (int kk = 0; kk < 20; ++kk) {
      float w0 = w_lds[kk][tj * 2], w1 = w_lds[kk][tj * 2 + 1];
      float h0 = xh_lds[kk][tb * 2], h1 = xh_lds[kk][tb * 2 + 1];
      a00 += w0 * h0; a01 += w0 * h1;
      a10 += w1 * h0; a11 += w1 * h1;
    }
    __syncthreads();
  }
  int j0 = jbase + tj * 2, b0 = bbase + tb * 2;
  if (j0 < G3)     { out[b0 * G3 + j0] = a00;     out[(b0 + 1) * G3 + j0] = a01; }
  if (j0 + 1 < G3) { out[b0 * G3 + j0 + 1] = a10; out[(b0 + 1) * G3 + j0 + 1] = a11; }
}

// ---------------- pointwise GRU update ----------------
__global__ void k_hnew(const float* __restrict__ gi, const float* __restrict__ gh,
                       const float* __restrict__ b_ih, const float* __restrict__ b_hh,
                       const float* __restrict__ hprev, float* __restrict__ hnext,
                       float* __restrict__ hy, int t) {
  int idx = blockIdx.x * blockDim.x + threadIdx.x;
  if (idx >= B * HID) return;
  int b = idx / HID, i = idx % HID;
  float ir = gi[b * G3 + i]           + b_ih[i];
  float iz = gi[b * G3 + HID + i]     + b_ih[HID + i];
  float in_ = gi[b * G3 + 2 * HID + i] + b_ih[2 * HID + i];
  float hr = gh[b * G3 + i]           + b_hh[i];
  float hz = gh[b * G3 + HID + i]     + b_hh[HID + i];
  float hn = gh[b * G3 + 2 * HID + i] + b_hh[2 * HID + i];
  float r  = 1.0f / (1.0f + expf(-(ir + hr)));
  float zg = 1.0f / (1.0f + expf(-(iz + hz)));
  float n  = tanhf(in_ + r * hn);
  float h  = (1.0f - zg) * n + zg * hprev[idx];
  hnext[idx] = h;
  hy[(size_t)b * SEQ * HID + (size_t)t * HID + i] = h;
}

// ---------------- logits GEMM + gumbel + argmax (fused) ----------------
// tile 64v x 256b, 256 threads, 8x8 micro-tile, Kt=20 (700=35*20)
// LDS rows padded +4 dwords (keeps 16B alignment for float4 reads, banks
// skewed by 4*kk). ALL accumulator indexing is compile-time (full unroll) so
// acc[][] stays in VGPRs -- runtime indexing sent it to scratch (3.1 GB/disp
// of spill writes in round 1).
#define WPITCH 68    // 64+4 dwords
#define HPITCH 260   // 256+4 dwords
__global__ __launch_bounds__(256)
void k_logits(const float* __restrict__ h, const float* __restrict__ out_w,
              const float* __restrict__ out_b, const uint32_t* __restrict__ keys,
              unsigned long long* __restrict__ slot, int t) {
  __shared__ float w_lds[20][WPITCH];
  __shared__ float h_lds[20][HPITCH];
  const int vbase = blockIdx.x * 64;
  const int tid = threadIdx.x;
  const int tv = tid % 8, tb = tid / 8;  // v = vbase+tv*8+iv ; b = tb*8+ib
  float acc[8][8];
#pragma unroll
  for (int i = 0; i < 8; ++i)
#pragma unroll
    for (int j = 0; j < 8; ++j) acc[i][j] = 0.f;

  for (int k0 = 0; k0 < HID; k0 += 20) {
    for (int idx = tid; idx < 64 * 20; idx += 256) {
      int vv = idx / 20, kk = idx % 20;
      int v = vbase + vv;
      w_lds[kk][vv] = (v < VOCAB) ? out_w[(size_t)v * HID + k0 + kk] : 0.0f;
    }
    for (int idx = tid; idx < 256 * 20; idx += 256) {
      int bb = idx / 20, kk = idx % 20;
      h_lds[kk][bb] = h[bb * HID + k0 + kk];
    }
    __syncthreads();
#pragma unroll
    for (int kk = 0; kk < 20; ++kk) {
      float wv[8], hv[8];
      *(float4*)&wv[0] = *(const float4*)&w_lds[kk][tv * 8];
      *(float4*)&wv[4] = *(const float4*)&w_lds[kk][tv * 8 + 4];
      *(float4*)&hv[0] = *(const float4*)&h_lds[kk][tb * 8];
      *(float4*)&hv[4] = *(const float4*)&h_lds[kk][tb * 8 + 4];
#pragma unroll
      for (int iv = 0; iv < 8; ++iv)
#pragma unroll
        for (int ib = 0; ib < 8; ++ib) acc[iv][ib] += wv[iv] * hv[ib];
    }
    __syncthreads();
  }

  const uint32_t key0 = keys[2 * t], key1 = keys[2 * t + 1];
#pragma unroll
  for (int ib = 0; ib < 8; ++ib) {
    const int b = tb * 8 + ib;
    unsigned long long best = 0ull;
#pragma unroll
    for (int iv = 0; iv < 8; ++iv) {
      int v = vbase + tv * 8 + iv;
      if (v >= VOCAB) continue;
      float s = acc[iv][ib] + out_b[v];
      // JAX partitionable random_bits: bits = o0 ^ o1 of threefry(key, (0, j))
      uint32_t j = (uint32_t)(b * VOCAB + v);
      uint32_t o0, o1;
      threefry2x32(key0, key1, 0u, j, o0, o1);
      uint32_t bits = o0 ^ o1;
      float f = __uint_as_float((bits >> 9) | 0x3f800000u) - 1.0f;
      float u = fmaxf(f, 1.17549435e-38f);
      float g = -logf(-logf(u));
      s += g;
      uint32_t us = __float_as_uint(s);
      us = (us & 0x80000000u) ? ~us : (us | 0x80000000u);
      unsigned long long cand =
          ((unsigned long long)us << 32) | (uint32_t)(~(uint32_t)v);  // first-index tie-break
      if (cand > best) best = cand;
    }
    // reduce across the 8 tv lanes (contiguous lanes within the wave)
#pragma unroll
    for (int off = 1; off < 8; off <<= 1) {
      unsigned long long other = __shfl_xor(best, off, 64);
      if (other > best) best = other;
    }
    if (tv == 0) atomicMax(&slot[b], best);
  }
}

// ---------------- token extraction ----------------
__global__ void k_tok(const unsigned long long* __restrict__ slot,
                      int* __restrict__ tok_next, float* __restrict__ y_out, int t) {
  int b = threadIdx.x;
  unsigned long long p = slot[b];
  uint32_t v = ~((uint32_t)(p & 0xFFFFFFFFull));
  tok_next[b] = (int)v;
  y_out[b * SEQ + t] = (float)v;
}

// ---------------- host launch ----------------
extern "C" void kernel_launch(void* const* d_in, const int* in_sizes, int n_in,
                              void* d_out, int out_size, void* d_ws, size_t ws_size,
                              hipStream_t stream) {
  const float* z      = (const float*)d_in[0];
  const int*   l      = (const int*)  d_in[1];
  const float* emb_w  = (const float*)d_in[2];
  const float* attr_w = (const float*)d_in[3];
  const float* W_ih   = (const float*)d_in[4];
  const float* W_hh   = (const float*)d_in[5];
  const float* b_ih   = (const float*)d_in[6];
  const float* b_hh   = (const float*)d_in[7];
  const float* out_w  = (const float*)d_in[8];
  const float* out_b  = (const float*)d_in[9];

  float* hy    = (float*)d_out;
  float* y_out = (float*)d_out + HY_ELEMS;

  char* ws = (char*)d_ws;
  uint32_t* keys            = (uint32_t*)ws;                         // 256 B
  unsigned long long* slots = (unsigned long long*)(ws + 256);       // 30*256*8 = 61440
  int* tokbuf               = (int*)(ws + 256 + 61440);              // 32*256*4 = 32768
  float* hbuf               = (float*)(ws + 256 + 61440 + 32768);    // 2*B*HID*4
  float* gi                 = hbuf + 2 * B * HID;                    // B*G3
  float* gh                 = gi + B * G3;                           // B*G3

  k_init<<<(B * HID + 255) / 256, 256, 0, stream>>>(z, l, attr_w, hbuf, keys, slots,
                                                    tokbuf, y_out);

  for (int t = 0; t <= MAXLEN; ++t) {
    float* hprev = hbuf + (t % 2) * B * HID;
    float* hnext = hbuf + ((t + 1) % 2) * B * HID;
    const int* tok_t = tokbuf + ((t == MAXLEN) ? 31 : t) * B;

    dim3 ggrid(66, 8, 2);
    k_gates<<<ggrid, 256, 0, stream>>>(W_ih, W_hh, emb_w, hprev, tok_t, gi, gh);
    k_hnew<<<(B * HID + 255) / 256, 256, 0, stream>>>(gi, gh, b_ih, b_hh, hprev,
                                                      hnext, hy, t);
    if (t < MAXLEN) {
      k_logits<<<(VOCAB + 63) / 64, 256, 0, stream>>>(hnext, out_w, out_b, keys,
                                                      slots + (size_t)t * B, t);
      k_tok<<<1, 256, 0, stream>>>(slots + (size_t)t * B, tokbuf + (t + 1) * B,
                                   y_out, t);
    }
  }
}

// Round 3
// 7479.925 us; speedup vs baseline: 5.6707x; 2.6914x over previous
//
#include <hip/hip_runtime.h>
#include <stdint.h>

#define VOCAB 50257
#define B 256
#define EMB 300
#define HID 700
#define G3 2100          // 3*HID
#define ZDIM 500
#define ATTR_EMBD 200
#define MAXLEN 30
#define SEQ 31           // MAXLEN+1
#define HY_ELEMS (B*SEQ*HID)
#define KP 704           // HID padded to mult of 32
#define VPAD 50304       // VOCAB padded to mult of 128 (393*128)

typedef _Float16 half8 __attribute__((ext_vector_type(8)));
typedef _Float16 half4 __attribute__((ext_vector_type(4)));
typedef float f32x4 __attribute__((ext_vector_type(4)));

// ---------------- threefry2x32 (JAX-exact, 20 rounds) ----------------
__device__ __forceinline__ uint32_t rotl32(uint32_t x, int r) {
  return (x << r) | (x >> (32 - r));
}

__device__ __forceinline__ void threefry2x32(uint32_t k0, uint32_t k1,
                                             uint32_t x0, uint32_t x1,
                                             uint32_t& o0, uint32_t& o1) {
  const uint32_t ks2 = k0 ^ k1 ^ 0x1BD11BDAu;
  x0 += k0; x1 += k1;
#define TF_R4(a, b, c, d)                                     \
  x0 += x1; x1 = rotl32(x1, a); x1 ^= x0;                     \
  x0 += x1; x1 = rotl32(x1, b); x1 ^= x0;                     \
  x0 += x1; x1 = rotl32(x1, c); x1 ^= x0;                     \
  x0 += x1; x1 = rotl32(x1, d); x1 ^= x0;
  TF_R4(13, 15, 26, 6)  x0 += k1;  x1 += ks2 + 1u;
  TF_R4(17, 29, 16, 24) x0 += ks2; x1 += k0 + 2u;
  TF_R4(13, 15, 26, 6)  x0 += k0;  x1 += k1 + 3u;
  TF_R4(17, 29, 16, 24) x0 += k1;  x1 += ks2 + 4u;
  TF_R4(13, 15, 26, 6)  x0 += ks2; x1 += k0 + 5u;
#undef TF_R4
  o0 = x0; o1 = x1;
}

// gumbel + monotone pack (shared by both logits kernels)
__device__ __forceinline__ unsigned long long gumbel_pack(float s, uint32_t key0,
                                                          uint32_t key1, int b, int v) {
  uint32_t j = (uint32_t)(b * VOCAB + v);
  uint32_t o0, o1;
  threefry2x32(key0, key1, 0u, j, o0, o1);
  uint32_t bits = o0 ^ o1;
  float f = __uint_as_float((bits >> 9) | 0x3f800000u) - 1.0f;
  float u = fmaxf(f, 1.17549435e-38f);
  float g = -logf(-logf(u));
  s += g;
  uint32_t us = __float_as_uint(s);
  us = (us & 0x80000000u) ? ~us : (us | 0x80000000u);
  return ((unsigned long long)us << 32) | (uint32_t)(~(uint32_t)v);
}

// ---------------- init ----------------
__global__ void k_init(const float* __restrict__ z, const int* __restrict__ l,
                       const float* __restrict__ attr_w,
                       float* __restrict__ hbuf0, uint32_t* __restrict__ keys,
                       unsigned long long* __restrict__ slots,
                       int* __restrict__ tok, float* __restrict__ y_out,
                       _Float16* __restrict__ h_hi, _Float16* __restrict__ h_lo) {
  int idx = blockIdx.x * blockDim.x + threadIdx.x;
  if (idx < B * HID) {
    int b = idx / HID, i = idx % HID;
    float v = (i < ZDIM) ? z[b * ZDIM + i]
                         : attr_w[l[b] * ATTR_EMBD + (i - ZDIM)];
    hbuf0[idx] = v;
  }
  if (idx < MAXLEN) {
    uint32_t o0, o1;
    threefry2x32(0u, 42u, 0u, (uint32_t)idx, o0, o1);
    keys[2 * idx] = o0; keys[2 * idx + 1] = o1;
  }
  if (idx < MAXLEN * B) slots[idx] = 0ull;
  if (idx < B) {
    tok[idx] = 1;
    tok[31 * B + idx] = 2;
    y_out[idx * SEQ + MAXLEN] = 2.0f;
  }
  // zero the k-padding (700..703) of the h split arrays
  if (idx < B * 4) {
    int b = idx >> 2, k = HID + (idx & 3);
    h_hi[b * KP + k] = (_Float16)0.0f;
    h_lo[b * KP + k] = (_Float16)0.0f;
  }
}

// ---------------- w split precompute: W=64*w -> hi + lo/2048 (fp16) ----------------
__global__ void k_wsplit(const float* __restrict__ out_w,
                         _Float16* __restrict__ w_hi, _Float16* __restrict__ w_lo) {
  size_t idx = (size_t)blockIdx.x * blockDim.x + threadIdx.x;  // one per 4 elems
  size_t i4 = idx * 4;
  if (i4 >= (size_t)VPAD * KP) return;
  int v = (int)(i4 / KP), k = (int)(i4 % KP);
  float x[4];
  if (v < VOCAB && k + 3 < HID) {
    const float4 xv = *(const float4*)&out_w[(size_t)v * HID + k];
    x[0] = xv.x; x[1] = xv.y; x[2] = xv.z; x[3] = xv.w;
  } else {
#pragma unroll
    for (int j = 0; j < 4; ++j)
      x[j] = (v < VOCAB && k + j < HID) ? out_w[(size_t)v * HID + k + j] : 0.0f;
  }
  half4 hi, lo;
#pragma unroll
  for (int j = 0; j < 4; ++j) {
    float xs = x[j] * 64.0f;
    _Float16 h = (_Float16)xs;
    hi[j] = h;
    lo[j] = (_Float16)((xs - (float)h) * 2048.0f);
  }
  *(half4*)&w_hi[i4] = hi;
  *(half4*)&w_lo[i4] = lo;
}

// ---------------- gates GEMM (fp32, unchanged) ----------------
__global__ void k_gates(const float* __restrict__ W_ih, const float* __restrict__ W_hh,
                        const float* __restrict__ emb_w, const float* __restrict__ hprev,
                        const int* __restrict__ tok,
                        float* __restrict__ gi, float* __restrict__ gh) {
  const int zz = blockIdx.z;
  const float* __restrict__ W = zz ? W_hh : W_ih;
  const int K = zz ? HID : EMB;
  float* __restrict__ out = zz ? gh : gi;
  __shared__ float w_lds[20][36];
  __shared__ float xh_lds[20][36];
  const int jbase = blockIdx.x * 32;
  const int bbase = blockIdx.y * 32;
  const int tid = threadIdx.x;
  const int tj = tid % 16, tb = tid / 16;
  float a00 = 0.f, a01 = 0.f, a10 = 0.f, a11 = 0.f;
  for (int k0 = 0; k0 < K; k0 += 20) {
    for (int idx = tid; idx < 640; idx += 256) {
      int col = idx / 20, kk = idx % 20;
      int j = jbase + col;
      w_lds[kk][col] = (j < G3) ? W[j * K + k0 + kk] : 0.0f;
      int b = bbase + col;
      float xv;
      if (zz) xv = hprev[b * HID + k0 + kk];
      else    xv = emb_w[tok[b] * EMB + k0 + kk];
      xh_lds[kk][col] = xv;
    }
    __syncthreads();
#pragma unroll
    for (int kk = 0; kk < 20; ++kk) {
      float w0 = w_lds[kk][tj * 2], w1 = w_lds[kk][tj * 2 + 1];
      float h0 = xh_lds[kk][tb * 2], h1 = xh_lds[kk][tb * 2 + 1];
      a00 += w0 * h0; a01 += w0 * h1;
      a10 += w1 * h0; a11 += w1 * h1;
    }
    __syncthreads();
  }
  int j0 = jbase + tj * 2, b0 = bbase + tb * 2;
  if (j0 < G3)     { out[b0 * G3 + j0] = a00;     out[(b0 + 1) * G3 + j0] = a01; }
  if (j0 + 1 < G3) { out[b0 * G3 + j0 + 1] = a10; out[(b0 + 1) * G3 + j0 + 1] = a11; }
}

// ---------------- pointwise GRU update + h fp16-split for the MFMA GEMM ----------------
__global__ void k_hnew(const float* __restrict__ gi, const float* __restrict__ gh,
                       const float* __restrict__ b_ih, const float* __restrict__ b_hh,
                       const float* __restrict__ hprev, float* __restrict__ hnext,
                       float* __restrict__ hy, _Float16* __restrict__ h_hi,
                       _Float16* __restrict__ h_lo, int t) {
  int idx = blockIdx.x * blockDim.x + threadIdx.x;
  if (idx >= B * HID) return;
  int b = idx / HID, i = idx % HID;
  float ir = gi[b * G3 + i]            + b_ih[i];
  float iz = gi[b * G3 + HID + i]      + b_ih[HID + i];
  float in_ = gi[b * G3 + 2 * HID + i] + b_ih[2 * HID + i];
  float hr = gh[b * G3 + i]            + b_hh[i];
  float hz = gh[b * G3 + HID + i]      + b_hh[HID + i];
  float hn = gh[b * G3 + 2 * HID + i]  + b_hh[2 * HID + i];
  float r  = 1.0f / (1.0f + expf(-(ir + hr)));
  float zg = 1.0f / (1.0f + expf(-(iz + hz)));
  float n  = tanhf(in_ + r * hn);
  float h  = (1.0f - zg) * n + zg * hprev[idx];
  hnext[idx] = h;
  hy[(size_t)b * SEQ * HID + (size_t)t * HID + i] = h;
  // fp16 split of H = 8*h (for next logits step)
  float hs = h * 8.0f;
  _Float16 hh = (_Float16)hs;
  h_hi[b * KP + i] = hh;
  h_lo[b * KP + i] = (_Float16)((hs - (float)hh) * 2048.0f);
}

// ---------------- MFMA logits: 128v x 128b block, 4 waves (64x64 each) ----------------
// logits = (acc_hi + acc_x/2048) / 512 + out_b;  K padded to 704.
// LDS tile layout [kc(4)][row(128)][8 fp16 = 16B]: fragment reads are 16
// consecutive 16B slots per quarter-wave -> 2-way bank aliasing (free).
__global__ __launch_bounds__(256, 2)
void k_logits_mfma(const _Float16* __restrict__ w_hi, const _Float16* __restrict__ w_lo,
                   const _Float16* __restrict__ h_hi, const _Float16* __restrict__ h_lo,
                   const float* __restrict__ out_b, const uint32_t* __restrict__ keys,
                   unsigned long long* __restrict__ slot, int t) {
  __shared__ float4 lwhi[512];
  __shared__ float4 lwlo[512];
  __shared__ float4 lhhi[512];
  __shared__ float4 lhlo[512];
  const int tid = threadIdx.x;
  const int lane = tid & 63;
  const int wid = tid >> 6;
  const int wv = wid >> 1, wb = wid & 1;   // wave tile: v = wv*64.., b = wb*64..
  const int vbase = blockIdx.y * 128;
  const int bbase = blockIdx.x * 128;

  // staging slot assignment: slot = kc*128 + row ; this thread owns slots tid, tid+256
  const int row_s = tid & 127;
  const int kc_s = tid >> 7;                    // 0/1 ; second slot kc_s+2
  const size_t wrow = (size_t)(vbase + row_s) * KP;
  const size_t hrow = (size_t)(bbase + row_s) * KP;

  f32x4 acc_h[4][4];
  f32x4 acc_x[4][4];
#pragma unroll
  for (int i = 0; i < 4; ++i)
#pragma unroll
    for (int j = 0; j < 4; ++j) {
      acc_h[i][j] = (f32x4)0.0f;
      acc_x[i][j] = (f32x4)0.0f;
    }

  for (int k0 = 0; k0 < KP; k0 += 32) {
    // global -> regs
    const int ka = k0 + kc_s * 8, kb = k0 + (kc_s + 2) * 8;
    float4 g0 = *(const float4*)&w_hi[wrow + ka];
    float4 g1 = *(const float4*)&w_hi[wrow + kb];
    float4 g2 = *(const float4*)&w_lo[wrow + ka];
    float4 g3 = *(const float4*)&w_lo[wrow + kb];
    float4 g4 = *(const float4*)&h_hi[hrow + ka];
    float4 g5 = *(const float4*)&h_hi[hrow + kb];
    float4 g6 = *(const float4*)&h_lo[hrow + ka];
    float4 g7 = *(const float4*)&h_lo[hrow + kb];
    __syncthreads();     // previous iteration's fragment reads complete
    lwhi[tid] = g0; lwhi[tid + 256] = g1;
    lwlo[tid] = g2; lwlo[tid + 256] = g3;
    lhhi[tid] = g4; lhhi[tid + 256] = g5;
    lhlo[tid] = g6; lhlo[tid + 256] = g7;
    __syncthreads();

    // fragment reads: slot = (lane>>4)*128 + row
    const int kcf = (lane >> 4) * 128 + (lane & 15);
    half8 a_hi[4], a_lo[4];
#pragma unroll
    for (int fv = 0; fv < 4; ++fv) {
      int s = kcf + wv * 64 + fv * 16;
      a_hi[fv] = *(const half8*)&lwhi[s];
      a_lo[fv] = *(const half8*)&lwlo[s];
    }
#pragma unroll
    for (int fb = 0; fb < 4; ++fb) {
      int s = kcf + wb * 64 + fb * 16;
      half8 b_hi = *(const half8*)&lhhi[s];
      half8 b_lo = *(const half8*)&lhlo[s];
#pragma unroll
      for (int fv = 0; fv < 4; ++fv) {
        acc_h[fv][fb] = __builtin_amdgcn_mfma_f32_16x16x32_f16(a_hi[fv], b_hi,
                                                               acc_h[fv][fb], 0, 0, 0);
        acc_x[fv][fb] = __builtin_amdgcn_mfma_f32_16x16x32_f16(a_hi[fv], b_lo,
                                                               acc_x[fv][fb], 0, 0, 0);
        acc_x[fv][fb] = __builtin_amdgcn_mfma_f32_16x16x32_f16(a_lo[fv], b_hi,
                                                               acc_x[fv][fb], 0, 0, 0);
      }
    }
  }

  // epilogue: logits + gumbel + argmax
  const uint32_t key0 = keys[2 * t], key1 = keys[2 * t + 1];
  const float c1 = 1.0f / 2048.0f, c2 = 1.0f / 512.0f;
#pragma unroll
  for (int fb = 0; fb < 4; ++fb) {
    const int b = bbase + wb * 64 + fb * 16 + (lane & 15);
    unsigned long long best = 0ull;
#pragma unroll
    for (int fv = 0; fv < 4; ++fv) {
#pragma unroll
      for (int r = 0; r < 4; ++r) {
        int v = vbase + wv * 64 + fv * 16 + (lane >> 4) * 4 + r;
        if (v < VOCAB) {
          float s = (acc_h[fv][fb][r] + acc_x[fv][fb][r] * c1) * c2 + out_b[v];
          unsigned long long cand = gumbel_pack(s, key0, key1, b, v);
          if (cand > best) best = cand;
        }
      }
    }
    // reduce across the 4 row-groups (lanes differing in bits 4,5)
    unsigned long long o;
    o = __shfl_xor(best, 16, 64); if (o > best) best = o;
    o = __shfl_xor(best, 32, 64); if (o > best) best = o;
    if ((lane >> 4) == 0) atomicMax(&slot[b], best);
  }
}

// ---------------- fp32 logits fallback (if workspace too small) ----------------
#define WPITCH 68
#define HPITCH 260
__global__ __launch_bounds__(256)
void k_logits_f32(const float* __restrict__ h, const float* __restrict__ out_w,
                  const float* __restrict__ out_b, const uint32_t* __restrict__ keys,
                  unsigned long long* __restrict__ slot, int t) {
  __shared__ float w_lds[20][WPITCH];
  __shared__ float h_lds[20][HPITCH];
  const int vbase = blockIdx.x * 64;
  const int tid = threadIdx.x;
  const int tv = tid % 8, tb = tid / 8;
  float acc[8][8];
#pragma unroll
  for (int i = 0; i < 8; ++i)
#pragma unroll
    for (int j = 0; j < 8; ++j) acc[i][j] = 0.f;

  for (int k0 = 0; k0 < HID; k0 += 20) {
    for (int idx = tid; idx < 64 * 20; idx += 256) {
      int vv = idx / 20, kk = idx % 20;
      int v = vbase + vv;
      w_lds[kk][vv] = (v < VOCAB) ? out_w[(size_t)v * HID + k0 + kk] : 0.0f;
    }
    for (int idx = tid; idx < 256 * 20; idx += 256) {
      int bb = idx / 20, kk = idx % 20;
      h_lds[kk][bb] = h[bb * HID + k0 + kk];
    }
    __syncthreads();
#pragma unroll
    for (int kk = 0; kk < 20; ++kk) {
      float wv[8], hv[8];
      *(float4*)&wv[0] = *(const float4*)&w_lds[kk][tv * 8];
      *(float4*)&wv[4] = *(const float4*)&w_lds[kk][tv * 8 + 4];
      *(float4*)&hv[0] = *(const float4*)&h_lds[kk][tb * 8];
      *(float4*)&hv[4] = *(const float4*)&h_lds[kk][tb * 8 + 4];
#pragma unroll
      for (int iv = 0; iv < 8; ++iv)
#pragma unroll
        for (int ib = 0; ib < 8; ++ib) acc[iv][ib] += wv[iv] * hv[ib];
    }
    __syncthreads();
  }

  const uint32_t key0 = keys[2 * t], key1 = keys[2 * t + 1];
#pragma unroll
  for (int ib = 0; ib < 8; ++ib) {
    const int b = tb * 8 + ib;
    unsigned long long best = 0ull;
#pragma unroll
    for (int iv = 0; iv < 8; ++iv) {
      int v = vbase + tv * 8 + iv;
      if (v >= VOCAB) continue;
      unsigned long long cand = gumbel_pack(acc[iv][ib] + out_b[v], key0, key1, b, v);
      if (cand > best) best = cand;
    }
#pragma unroll
    for (int off = 1; off < 8; off <<= 1) {
      unsigned long long other = __shfl_xor(best, off, 64);
      if (other > best) best = other;
    }
    if (tv == 0) atomicMax(&slot[b], best);
  }
}

// ---------------- token extraction ----------------
__global__ void k_tok(const unsigned long long* __restrict__ slot,
                      int* __restrict__ tok_next, float* __restrict__ y_out, int t) {
  int b = threadIdx.x;
  unsigned long long p = slot[b];
  uint32_t v = ~((uint32_t)(p & 0xFFFFFFFFull));
  tok_next[b] = (int)v;
  y_out[b * SEQ + t] = (float)v;
}

// ---------------- host launch ----------------
extern "C" void kernel_launch(void* const* d_in, const int* in_sizes, int n_in,
                              void* d_out, int out_size, void* d_ws, size_t ws_size,
                              hipStream_t stream) {
  const float* z      = (const float*)d_in[0];
  const int*   l      = (const int*)  d_in[1];
  const float* emb_w  = (const float*)d_in[2];
  const float* attr_w = (const float*)d_in[3];
  const float* W_ih   = (const float*)d_in[4];
  const float* W_hh   = (const float*)d_in[5];
  const float* b_ih   = (const float*)d_in[6];
  const float* b_hh   = (const float*)d_in[7];
  const float* out_w  = (const float*)d_in[8];
  const float* out_b  = (const float*)d_in[9];

  float* hy    = (float*)d_out;
  float* y_out = (float*)d_out + HY_ELEMS;

  char* ws = (char*)d_ws;
  size_t off = 0;
  uint32_t* keys            = (uint32_t*)(ws + off);           off += 256;
  unsigned long long* slots = (unsigned long long*)(ws + off); off += (size_t)MAXLEN * B * 8;
  int* tokbuf               = (int*)(ws + off);                off += (size_t)32 * B * 4;
  float* hbuf               = (float*)(ws + off);              off += (size_t)2 * B * HID * 4;
  float* gi                 = (float*)(ws + off);              off += (size_t)B * G3 * 4;
  float* gh                 = (float*)(ws + off);              off += (size_t)B * G3 * 4;
  _Float16* h_hi            = (_Float16*)(ws + off);           off += (size_t)B * KP * 2;
  _Float16* h_lo            = (_Float16*)(ws + off);           off += (size_t)B * KP * 2;
  _Float16* w_hi            = (_Float16*)(ws + off);           off += (size_t)VPAD * KP * 2;
  _Float16* w_lo            = (_Float16*)(ws + off);           off += (size_t)VPAD * KP * 2;
  const bool use_mfma = (ws_size >= off);

  k_init<<<(B * HID + 255) / 256, 256, 0, stream>>>(z, l, attr_w, hbuf, keys, slots,
                                                    tokbuf, y_out, h_hi, h_lo);
  if (use_mfma) {
    int nthr4 = (int)(((size_t)VPAD * KP / 4 + 255) / 256);
    k_wsplit<<<nthr4, 256, 0, stream>>>(out_w, w_hi, w_lo);
  }

  for (int t = 0; t <= MAXLEN; ++t) {
    float* hprev = hbuf + (t % 2) * B * HID;
    float* hnext = hbuf + ((t + 1) % 2) * B * HID;
    const int* tok_t = tokbuf + ((t == MAXLEN) ? 31 : t) * B;

    dim3 ggrid(66, 8, 2);
    k_gates<<<ggrid, 256, 0, stream>>>(W_ih, W_hh, emb_w, hprev, tok_t, gi, gh);
    k_hnew<<<(B * HID + 255) / 256, 256, 0, stream>>>(gi, gh, b_ih, b_hh, hprev,
                                                      hnext, hy, h_hi, h_lo, t);
    if (t < MAXLEN) {
      if (use_mfma) {
        dim3 lgrid(2, VPAD / 128);
        k_logits_mfma<<<lgrid, 256, 0, stream>>>(w_hi, w_lo, h_hi, h_lo, out_b, keys,
                                                 slots + (size_t)t * B, t);
      } else {
        k_logits_f32<<<(VOCAB + 63) / 64, 256, 0, stream>>>(hnext, out_w, out_b, keys,
                                                            slots + (size_t)t * B, t);
      }
      k_tok<<<1, 256, 0, stream>>>(slots + (size_t)t * B, tokbuf + (t + 1) * B,
                                   y_out, t);
    }
  }
}

// Round 5
// 4931.678 us; speedup vs baseline: 8.6008x; 1.5167x over previous
//
#include <hip/hip_runtime.h>
#include <stdint.h>

#define VOCAB 50257
#define B 256
#define EMB 300
#define HID 700
#define G3 2100          // 3*HID
#define ZDIM 500
#define ATTR_EMBD 200
#define MAXLEN 30
#define SEQ 31           // MAXLEN+1
#define HY_ELEMS (B*SEQ*HID)
#define KP 704           // HID padded to mult of 32
#define KIH 320          // EMB padded to mult of 32
#define VPAD 50304       // VOCAB padded to mult of 128 (393*128)
#define NVT 393          // VPAD/128
#define MPAD 2112        // G3 padded to 33*64
#define SOS_IDX 1
#define EOS_IDX 2

typedef _Float16 half8 __attribute__((ext_vector_type(8)));
typedef _Float16 half4 __attribute__((ext_vector_type(4)));
typedef float f32x4 __attribute__((ext_vector_type(4)));

// ---------------- global_load_lds helper (16B per lane, dest = wave base + lane*16)
typedef const __attribute__((address_space(1))) void* gas1_t;
typedef __attribute__((address_space(3))) void* las3_t;
__device__ __forceinline__ void gload_lds16(const void* g, void* l) {
  __builtin_amdgcn_global_load_lds((gas1_t)g, (las3_t)l, 16, 0, 0);
}

// ---------------- threefry2x32 (JAX-exact, 20 rounds) ----------------
__device__ __forceinline__ uint32_t rotl32(uint32_t x, int r) {
  return (x << r) | (x >> (32 - r));
}

__device__ __forceinline__ void threefry2x32(uint32_t k0, uint32_t k1,
                                             uint32_t x0, uint32_t x1,
                                             uint32_t& o0, uint32_t& o1) {
  const uint32_t ks2 = k0 ^ k1 ^ 0x1BD11BDAu;
  x0 += k0; x1 += k1;
#define TF_R4(a, b, c, d)                                     \
  x0 += x1; x1 = rotl32(x1, a); x1 ^= x0;                     \
  x0 += x1; x1 = rotl32(x1, b); x1 ^= x0;                     \
  x0 += x1; x1 = rotl32(x1, c); x1 ^= x0;                     \
  x0 += x1; x1 = rotl32(x1, d); x1 ^= x0;
  TF_R4(13, 15, 26, 6)  x0 += k1;  x1 += ks2 + 1u;
  TF_R4(17, 29, 16, 24) x0 += ks2; x1 += k0 + 2u;
  TF_R4(13, 15, 26, 6)  x0 += k0;  x1 += k1 + 3u;
  TF_R4(17, 29, 16, 24) x0 += k1;  x1 += ks2 + 4u;
  TF_R4(13, 15, 26, 6)  x0 += ks2; x1 += k0 + 5u;
#undef TF_R4
  o0 = x0; o1 = x1;
}

__device__ __forceinline__ unsigned long long gumbel_pack(float s, uint32_t key0,
                                                          uint32_t key1, int b, int v) {
  uint32_t j = (uint32_t)(b * VOCAB + v);
  uint32_t o0, o1;
  threefry2x32(key0, key1, 0u, j, o0, o1);
  uint32_t bits = o0 ^ o1;
  float f = __uint_as_float((bits >> 9) | 0x3f800000u) - 1.0f;
  float u = fmaxf(f, 1.17549435e-38f);
  float g = -logf(-logf(u));
  s += g;
  uint32_t us = __float_as_uint(s);
  us = (us & 0x80000000u) ? ~us : (us | 0x80000000u);
  return ((unsigned long long)us << 32) | (uint32_t)(~(uint32_t)v);
}

// split helper: val*scale -> {fp16 hi, fp16 lo=residual*2048} (returned by value;
// reference-out version can't bind to ext_vector elements)
struct hl16 { _Float16 hi, lo; };
__device__ __forceinline__ hl16 split16(float val, float scale) {
  float s = val * scale;
  _Float16 h = (_Float16)s;
  hl16 r;
  r.hi = h;
  r.lo = (_Float16)((s - (float)h) * 2048.0f);
  return r;
}

// ---------------- init ----------------
__global__ void k_init(const float* __restrict__ z, const int* __restrict__ l,
                       const float* __restrict__ attr_w, const float* __restrict__ emb_w,
                       float* __restrict__ hbuf0, uint32_t* __restrict__ keys,
                       unsigned long long* __restrict__ slots,
                       int* __restrict__ tok, float* __restrict__ y_out,
                       _Float16* __restrict__ h_hi, _Float16* __restrict__ h_lo,
                       _Float16* __restrict__ x0_hi, _Float16* __restrict__ x0_lo,
                       _Float16* __restrict__ xe_hi, _Float16* __restrict__ xe_lo,
                       int full) {
  int idx = blockIdx.x * blockDim.x + threadIdx.x;
  if (idx < B * HID) {
    int b = idx / HID, i = idx % HID;
    float v = (i < ZDIM) ? z[b * ZDIM + i]
                         : attr_w[l[b] * ATTR_EMBD + (i - ZDIM)];
    hbuf0[idx] = v;
    hl16 r = split16(v, 8.0f);
    h_hi[b * KP + i] = r.hi;
    h_lo[b * KP + i] = r.lo;
  }
  if (idx < MAXLEN) {
    uint32_t o0, o1;
    threefry2x32(0u, 42u, 0u, (uint32_t)idx, o0, o1);
    keys[2 * idx] = o0; keys[2 * idx + 1] = o1;
  }
  if (idx < MAXLEN * B) slots[idx] = 0ull;
  if (idx < B) {
    tok[idx] = SOS_IDX;
    tok[31 * B + idx] = EOS_IDX;
    y_out[idx * SEQ + MAXLEN] = 2.0f;
  }
  if (idx < B * 4) {  // zero k-pad of h split
    int b = idx >> 2, k = HID + (idx & 3);
    h_hi[b * KP + k] = (_Float16)0.0f;
    h_lo[b * KP + k] = (_Float16)0.0f;
  }
  if (full && idx < KIH) {
    float v0 = (idx < EMB) ? emb_w[SOS_IDX * EMB + idx] : 0.0f;
    float ve = (idx < EMB) ? emb_w[EOS_IDX * EMB + idx] : 0.0f;
    hl16 r0 = split16(v0, 8.0f);
    hl16 re = split16(ve, 8.0f);
    for (int b = 0; b < B; ++b) {  // broadcast rows (all batches share SOS/EOS)
      x0_hi[b * KIH + idx] = r0.hi; x0_lo[b * KIH + idx] = r0.lo;
      xe_hi[b * KIH + idx] = re.hi; xe_lo[b * KIH + idx] = re.lo;
    }
  }
}

// ---------------- logits w split: W=64*w -> hi + lo/2048 (fp16), VPADxKP ----------------
__global__ void k_wsplit(const float* __restrict__ out_w,
                         _Float16* __restrict__ w_hi, _Float16* __restrict__ w_lo) {
  size_t idx = (size_t)blockIdx.x * blockDim.x + threadIdx.x;
  size_t i4 = idx * 4;
  if (i4 >= (size_t)VPAD * KP) return;
  int v = (int)(i4 / KP), k = (int)(i4 % KP);
  float x[4];
  if (v < VOCAB && k + 3 < HID) {
    const float4 xv = *(const float4*)&out_w[(size_t)v * HID + k];
    x[0] = xv.x; x[1] = xv.y; x[2] = xv.z; x[3] = xv.w;
  } else {
#pragma unroll
    for (int j = 0; j < 4; ++j)
      x[j] = (v < VOCAB && k + j < HID) ? out_w[(size_t)v * HID + k + j] : 0.0f;
  }
  half4 hi, lo;
#pragma unroll
  for (int j = 0; j < 4; ++j) {
    hl16 r = split16(x[j], 64.0f);
    hi[j] = r.hi; lo[j] = r.lo;
  }
  *(half4*)&w_hi[i4] = hi;
  *(half4*)&w_lo[i4] = lo;
}

// ---------------- generic gate-weight split (Msrc x Ksrc -> MPAD x Kpad) ----------------
__global__ void k_gwsplit(const float* __restrict__ src, _Float16* __restrict__ hi,
                          _Float16* __restrict__ lo, int Msrc, int Ksrc, int Kpad,
                          int tot4) {
  int idx = blockIdx.x * blockDim.x + threadIdx.x;
  if (idx >= tot4) return;
  size_t i4 = (size_t)idx * 4;
  int m = (int)(i4 / Kpad), k = (int)(i4 % Kpad);
  half4 h, l;
#pragma unroll
  for (int j = 0; j < 4; ++j) {
    float x = (m < Msrc && k + j < Ksrc) ? src[(size_t)m * Ksrc + k + j] : 0.0f;
    hl16 r = split16(x, 64.0f);
    h[j] = r.hi; l[j] = r.lo;
  }
  *(half4*)&hi[i4] = h;
  *(half4*)&lo[i4] = l;
}

// ---------------- MFMA gates: 64j x 64b blocks, 4 waves (32x32), 2-phase gll+dbuf ----
__global__ __launch_bounds__(256, 4)
void k_gates2(const _Float16* __restrict__ wih_hi, const _Float16* __restrict__ wih_lo,
              const _Float16* __restrict__ whh_hi, const _Float16* __restrict__ whh_lo,
              const _Float16* __restrict__ x_hi, const _Float16* __restrict__ x_lo,
              const _Float16* __restrict__ h_hi, const _Float16* __restrict__ h_lo,
              float* __restrict__ gi, float* __restrict__ gh) {
  const int zz = blockIdx.z;
  const _Float16* __restrict__ Whi = zz ? whh_hi : wih_hi;
  const _Float16* __restrict__ Wlo = zz ? whh_lo : wih_lo;
  const _Float16* __restrict__ Xhi = zz ? h_hi : x_hi;
  const _Float16* __restrict__ Xlo = zz ? h_lo : x_lo;
  const int Kz = zz ? KP : KIH;
  float* __restrict__ out = zz ? gh : gi;

  const int jbase = blockIdx.x * 64;
  const int bbase = blockIdx.y * 64;
  __shared__ float4 lds[2][4][256];   // [buf][whi,wlo,xhi,xlo][kc*64+row]
  const int tid = threadIdx.x, lane = tid & 63, wid = tid >> 6;
  const int wj = wid >> 1, wb2 = wid & 1;
  const size_t wrow = (size_t)(jbase + lane) * Kz;   // stage: kc=wid, row=lane
  const size_t xrow = (size_t)(bbase + lane) * Kz;

  f32x4 acc_h[2][2], acc_x[2][2];
#pragma unroll
  for (int i = 0; i < 2; ++i)
#pragma unroll
    for (int j = 0; j < 2; ++j) { acc_h[i][j] = (f32x4)0.0f; acc_x[i][j] = (f32x4)0.0f; }

#define GSTAGE(bf, k0)                                                   \
  {                                                                      \
    gload_lds16(Whi + wrow + (k0) + wid * 8, &lds[bf][0][wid * 64]);     \
    gload_lds16(Wlo + wrow + (k0) + wid * 8, &lds[bf][1][wid * 64]);     \
    gload_lds16(Xhi + xrow + (k0) + wid * 8, &lds[bf][2][wid * 64]);     \
    gload_lds16(Xlo + xrow + (k0) + wid * 8, &lds[bf][3][wid * 64]);     \
  }

  const int nt = Kz / 32;
  GSTAGE(0, 0)
  for (int kt = 0; kt < nt; ++kt) {
    const int cur = kt & 1;
    __syncthreads();                       // drains staged loads for buf[cur]
    if (kt + 1 < nt) GSTAGE(cur ^ 1, (kt + 1) * 32)
    const int kcf = (lane >> 4) * 64 + (lane & 15);
    half8 a_hi[2], a_lo[2];
#pragma unroll
    for (int fv = 0; fv < 2; ++fv) {
      int s = kcf + wj * 32 + fv * 16;
      a_hi[fv] = *(const half8*)&lds[cur][0][s];
      a_lo[fv] = *(const half8*)&lds[cur][1][s];
    }
#pragma unroll
    for (int fb = 0; fb < 2; ++fb) {
      int s = kcf + wb2 * 32 + fb * 16;
      half8 b_hi = *(const half8*)&lds[cur][2][s];
      half8 b_lo = *(const half8*)&lds[cur][3][s];
#pragma unroll
      for (int fv = 0; fv < 2; ++fv) {
        acc_h[fv][fb] = __builtin_amdgcn_mfma_f32_16x16x32_f16(a_hi[fv], b_hi,
                                                               acc_h[fv][fb], 0, 0, 0);
        acc_x[fv][fb] = __builtin_amdgcn_mfma_f32_16x16x32_f16(a_hi[fv], b_lo,
                                                               acc_x[fv][fb], 0, 0, 0);
        acc_x[fv][fb] = __builtin_amdgcn_mfma_f32_16x16x32_f16(a_lo[fv], b_hi,
                                                               acc_x[fv][fb], 0, 0, 0);
      }
    }
  }
#undef GSTAGE

  const float c1 = 1.0f / 2048.0f, c2 = 1.0f / 512.0f;
#pragma unroll
  for (int fb = 0; fb < 2; ++fb) {
    const int b = bbase + wb2 * 32 + fb * 16 + (lane & 15);
#pragma unroll
    for (int fv = 0; fv < 2; ++fv) {
#pragma unroll
      for (int r = 0; r < 4; ++r) {
        int j = jbase + wj * 32 + fv * 16 + (lane >> 4) * 4 + r;
        if (j < G3)
          out[b * G3 + j] = (acc_h[fv][fb][r] + acc_x[fv][fb][r] * c1) * c2;
      }
    }
  }
}

// ---------------- fp32 gates fallback ----------------
__global__ void k_gates(const float* __restrict__ W_ih, const float* __restrict__ W_hh,
                        const float* __restrict__ emb_w, const float* __restrict__ hprev,
                        const int* __restrict__ tok,
                        float* __restrict__ gi, float* __restrict__ gh) {
  const int zz = blockIdx.z;
  const float* __restrict__ W = zz ? W_hh : W_ih;
  const int K = zz ? HID : EMB;
  float* __restrict__ out = zz ? gh : gi;
  __shared__ float w_lds[20][36];
  __shared__ float xh_lds[20][36];
  const int jbase = blockIdx.x * 32;
  const int bbase = blockIdx.y * 32;
  const int tid = threadIdx.x;
  const int tj = tid % 16, tb = tid / 16;
  float a00 = 0.f, a01 = 0.f, a10 = 0.f, a11 = 0.f;
  for (int k0 = 0; k0 < K; k0 += 20) {
    for (int idx = tid; idx < 640; idx += 256) {
      int col = idx / 20, kk = idx % 20;
      int j = jbase + col;
      w_lds[kk][col] = (j < G3) ? W[j * K + k0 + kk] : 0.0f;
      int b = bbase + col;
      float xv;
      if (zz) xv = hprev[b * HID + k0 + kk];
      else    xv = emb_w[tok[b] * EMB + k0 + kk];
      xh_lds[kk][col] = xv;
    }
    __syncthreads();
#pragma unroll
    for (int kk = 0; kk < 20; ++kk) {
      float w0 = w_lds[kk][tj * 2], w1 = w_lds[kk][tj * 2 + 1];
      float h0 = xh_lds[kk][tb * 2], h1 = xh_lds[kk][tb * 2 + 1];
      a00 += w0 * h0; a01 += w0 * h1;
      a10 += w1 * h0; a11 += w1 * h1;
    }
    __syncthreads();
  }
  int j0 = jbase + tj * 2, b0 = bbase + tb * 2;
  if (j0 < G3)     { out[b0 * G3 + j0] = a00;     out[(b0 + 1) * G3 + j0] = a01; }
  if (j0 + 1 < G3) { out[b0 * G3 + j0 + 1] = a10; out[(b0 + 1) * G3 + j0 + 1] = a11; }
}

// ---------------- pointwise GRU update + h fp16-split ----------------
__global__ void k_hnew(const float* __restrict__ gi, const float* __restrict__ gh,
                       const float* __restrict__ b_ih, const float* __restrict__ b_hh,
                       const float* __restrict__ hprev, float* __restrict__ hnext,
                       float* __restrict__ hy, _Float16* __restrict__ h_hi,
                       _Float16* __restrict__ h_lo, int t) {
  int idx = blockIdx.x * blockDim.x + threadIdx.x;
  if (idx >= B * HID) return;
  int b = idx / HID, i = idx % HID;
  float ir = gi[b * G3 + i]            + b_ih[i];
  float iz = gi[b * G3 + HID + i]      + b_ih[HID + i];
  float in_ = gi[b * G3 + 2 * HID + i] + b_ih[2 * HID + i];
  float hr = gh[b * G3 + i]            + b_hh[i];
  float hz = gh[b * G3 + HID + i]      + b_hh[HID + i];
  float hn = gh[b * G3 + 2 * HID + i]  + b_hh[2 * HID + i];
  float r  = 1.0f / (1.0f + expf(-(ir + hr)));
  float zg = 1.0f / (1.0f + expf(-(iz + hz)));
  float n  = tanhf(in_ + r * hn);
  float h  = (1.0f - zg) * n + zg * hprev[idx];
  hnext[idx] = h;
  hy[(size_t)b * SEQ * HID + (size_t)t * HID + i] = h;
  hl16 rr = split16(h, 8.0f);
  h_hi[b * KP + i] = rr.hi;
  h_lo[b * KP + i] = rr.lo;
}

// ---------------- MFMA logits v2: gll + dbuf + 2-phase, XCD pair swizzle ----------
// grid: 800 flat blocks; xcd = bid&7 owns 50 v-tiles, pair (c=0/1) shares w-panel.
__global__ __launch_bounds__(256, 2)
void k_logits2(const _Float16* __restrict__ w_hi, const _Float16* __restrict__ w_lo,
               const _Float16* __restrict__ h_hi, const _Float16* __restrict__ h_lo,
               const float* __restrict__ out_b, const uint32_t* __restrict__ keys,
               unsigned long long* __restrict__ slot, int t) {
  const int bid = blockIdx.x;
  const int xcd = bid & 7, li = bid >> 3;
  const int p = xcd * 50 + (li >> 1);
  if (p >= NVT) return;
  const int c = li & 1;
  const int vbase = p * 128, bbase = c * 128;

  __shared__ float4 lds[2][4][512];   // [buf][whi,wlo,hhi,hlo][kc*128+row]
  const int tid = threadIdx.x;
  const int lane = tid & 63;
  const int wid = tid >> 6;
  const int wv = wid >> 1, wb = wid & 1;

  // staging: wave covers slots [wid*64, +64) and [wid*64+256, +64)
  const int row0 = ((wid & 1) * 64) + lane;
  const int kc0 = wid >> 1;
  const size_t wrow = (size_t)(vbase + row0) * KP;
  const size_t hrow = (size_t)(bbase + row0) * KP;

  f32x4 acc_h[4][4];
  f32x4 acc_x[4][4];
#pragma unroll
  for (int i = 0; i < 4; ++i)
#pragma unroll
    for (int j = 0; j < 4; ++j) { acc_h[i][j] = (f32x4)0.0f; acc_x[i][j] = (f32x4)0.0f; }

#define LSTAGE(bf, k0)                                                           \
  {                                                                              \
    gload_lds16(w_hi + wrow + (k0) + kc0 * 8, &lds[bf][0][wid * 64]);            \
    gload_lds16(w_hi + wrow + (k0) + (kc0 + 2) * 8, &lds[bf][0][wid * 64 + 256]);\
    gload_lds16(w_lo + wrow + (k0) + kc0 * 8, &lds[bf][1][wid * 64]);            \
    gload_lds16(w_lo + wrow + (k0) + (kc0 + 2) * 8, &lds[bf][1][wid * 64 + 256]);\
    gload_lds16(h_hi + hrow + (k0) + kc0 * 8, &lds[bf][2][wid * 64]);            \
    gload_lds16(h_hi + hrow + (k0) + (kc0 + 2) * 8, &lds[bf][2][wid * 64 + 256]);\
    gload_lds16(h_lo + hrow + (k0) + kc0 * 8, &lds[bf][3][wid * 64]);            \
    gload_lds16(h_lo + hrow + (k0) + (kc0 + 2) * 8, &lds[bf][3][wid * 64 + 256]);\
  }

  const int nt = KP / 32;   // 22
  LSTAGE(0, 0)
  for (int kt = 0; kt < nt; ++kt) {
    const int cur = kt & 1;
    __syncthreads();                         // drains buf[cur]'s loads
    if (kt + 1 < nt) LSTAGE(cur ^ 1, (kt + 1) * 32)
    const int kcf = (lane >> 4) * 128 + (lane & 15);
    half8 a_hi[4], a_lo[4];
#pragma unroll
    for (int fv = 0; fv < 4; ++fv) {
      int s = kcf + wv * 64 + fv * 16;
      a_hi[fv] = *(const half8*)&lds[cur][0][s];
      a_lo[fv] = *(const half8*)&lds[cur][1][s];
    }
#pragma unroll
    for (int fb = 0; fb < 4; ++fb) {
      int s = kcf + wb * 64 + fb * 16;
      half8 b_hi = *(const half8*)&lds[cur][2][s];
      half8 b_lo = *(const half8*)&lds[cur][3][s];
#pragma unroll
      for (int fv = 0; fv < 4; ++fv) {
        acc_h[fv][fb] = __builtin_amdgcn_mfma_f32_16x16x32_f16(a_hi[fv], b_hi,
                                                               acc_h[fv][fb], 0, 0, 0);
        acc_x[fv][fb] = __builtin_amdgcn_mfma_f32_16x16x32_f16(a_hi[fv], b_lo,
                                                               acc_x[fv][fb], 0, 0, 0);
        acc_x[fv][fb] = __builtin_amdgcn_mfma_f32_16x16x32_f16(a_lo[fv], b_hi,
                                                               acc_x[fv][fb], 0, 0, 0);
      }
    }
  }
#undef LSTAGE

  const uint32_t key0 = keys[2 * t], key1 = keys[2 * t + 1];
  const float c1 = 1.0f / 2048.0f, c2 = 1.0f / 512.0f;
#pragma unroll
  for (int fb = 0; fb < 4; ++fb) {
    const int b = bbase + wb * 64 + fb * 16 + (lane & 15);
    unsigned long long best = 0ull;
#pragma unroll
    for (int fv = 0; fv < 4; ++fv) {
#pragma unroll
      for (int r = 0; r < 4; ++r) {
        int v = vbase + wv * 64 + fv * 16 + (lane >> 4) * 4 + r;
        if (v < VOCAB) {
          float s = (acc_h[fv][fb][r] + acc_x[fv][fb][r] * c1) * c2 + out_b[v];
          unsigned long long cand = gumbel_pack(s, key0, key1, b, v);
          if (cand > best) best = cand;
        }
      }
    }
    unsigned long long o;
    o = __shfl_xor(best, 16, 64); if (o > best) best = o;
    o = __shfl_xor(best, 32, 64); if (o > best) best = o;
    if ((lane >> 4) == 0) atomicMax(&slot[b], best);
  }
}

// ---------------- fp32 logits fallback ----------------
#define WPITCH 68
#define HPITCH 260
__global__ __launch_bounds__(256)
void k_logits_f32(const float* __restrict__ h, const float* __restrict__ out_w,
                  const float* __restrict__ out_b, const uint32_t* __restrict__ keys,
                  unsigned long long* __restrict__ slot, int t) {
  __shared__ float w_lds[20][WPITCH];
  __shared__ float h_lds[20][HPITCH];
  const int vbase = blockIdx.x * 64;
  const int tid = threadIdx.x;
  const int tv = tid % 8, tb = tid / 8;
  float acc[8][8];
#pragma unroll
  for (int i = 0; i < 8; ++i)
#pragma unroll
    for (int j = 0; j < 8; ++j) acc[i][j] = 0.f;

  for (int k0 = 0; k0 < HID; k0 += 20) {
    for (int idx = tid; idx < 64 * 20; idx += 256) {
      int vv = idx / 20, kk = idx % 20;
      int v = vbase + vv;
      w_lds[kk][vv] = (v < VOCAB) ? out_w[(size_t)v * HID + k0 + kk] : 0.0f;
    }
    for (int idx = tid; idx < 256 * 20; idx += 256) {
      int bb = idx / 20, kk = idx % 20;
      h_lds[kk][bb] = h[bb * HID + k0 + kk];
    }
    __syncthreads();
#pragma unroll
    for (int kk = 0; kk < 20; ++kk) {
      float wv[8], hv[8];
      *(float4*)&wv[0] = *(const float4*)&w_lds[kk][tv * 8];
      *(float4*)&wv[4] = *(const float4*)&w_lds[kk][tv * 8 + 4];
      *(float4*)&hv[0] = *(const float4*)&h_lds[kk][tb * 8];
      *(float4*)&hv[4] = *(const float4*)&h_lds[kk][tb * 8 + 4];
#pragma unroll
      for (int iv = 0; iv < 8; ++iv)
#pragma unroll
        for (int ib = 0; ib < 8; ++ib) acc[iv][ib] += wv[iv] * hv[ib];
    }
    __syncthreads();
  }

  const uint32_t key0 = keys[2 * t], key1 = keys[2 * t + 1];
#pragma unroll
  for (int ib = 0; ib < 8; ++ib) {
    const int b = tb * 8 + ib;
    unsigned long long best = 0ull;
#pragma unroll
    for (int iv = 0; iv < 8; ++iv) {
      int v = vbase + tv * 8 + iv;
      if (v >= VOCAB) continue;
      unsigned long long cand = gumbel_pack(acc[iv][ib] + out_b[v], key0, key1, b, v);
      if (cand > best) best = cand;
    }
#pragma unroll
    for (int off = 1; off < 8; off <<= 1) {
      unsigned long long other = __shfl_xor(best, off, 64);
      if (other > best) best = other;
    }
    if (tv == 0) atomicMax(&slot[b], best);
  }
}

// ---------------- token extraction + emb gather/split ----------------
__global__ void k_tok2(const unsigned long long* __restrict__ slot,
                       const float* __restrict__ emb_w,
                       int* __restrict__ tok_next, float* __restrict__ y_out,
                       _Float16* __restrict__ xc_hi, _Float16* __restrict__ xc_lo,
                       int t, int full) {
  const int b = blockIdx.x;
  const int c = threadIdx.x;   // 128 threads
  unsigned long long p = slot[b];
  uint32_t v = ~((uint32_t)(p & 0xFFFFFFFFull));
  if (c == 0) {
    tok_next[b] = (int)v;
    y_out[b * SEQ + t] = (float)v;
  }
  if (!full) return;
  if (c < 75) {
    float4 xv = *(const float4*)&emb_w[(size_t)v * EMB + c * 4];
    half4 hi, lo;
    hl16 r0 = split16(xv.x, 8.0f); hi[0] = r0.hi; lo[0] = r0.lo;
    hl16 r1 = split16(xv.y, 8.0f); hi[1] = r1.hi; lo[1] = r1.lo;
    hl16 r2 = split16(xv.z, 8.0f); hi[2] = r2.hi; lo[2] = r2.lo;
    hl16 r3 = split16(xv.w, 8.0f); hi[3] = r3.hi; lo[3] = r3.lo;
    *(half4*)&xc_hi[b * KIH + c * 4] = hi;
    *(half4*)&xc_lo[b * KIH + c * 4] = lo;
  } else if (c < 80) {
    *(half4*)&xc_hi[b * KIH + c * 4] = (half4)(_Float16)0.0f;
    *(half4*)&xc_lo[b * KIH + c * 4] = (half4)(_Float16)0.0f;
  }
}

// ---------------- host launch ----------------
extern "C" void kernel_launch(void* const* d_in, const int* in_sizes, int n_in,
                              void* d_out, int out_size, void* d_ws, size_t ws_size,
                              hipStream_t stream) {
  const float* z      = (const float*)d_in[0];
  const int*   l      = (const int*)  d_in[1];
  const float* emb_w  = (const float*)d_in[2];
  const float* attr_w = (const float*)d_in[3];
  const float* W_ih   = (const float*)d_in[4];
  const float* W_hh   = (const float*)d_in[5];
  const float* b_ih   = (const float*)d_in[6];
  const float* b_hh   = (const float*)d_in[7];
  const float* out_w  = (const float*)d_in[8];
  const float* out_b  = (const float*)d_in[9];

  float* hy    = (float*)d_out;
  float* y_out = (float*)d_out + HY_ELEMS;

  char* ws = (char*)d_ws;
  size_t off = 0;
  uint32_t* keys            = (uint32_t*)(ws + off);           off += 256;
  unsigned long long* slots = (unsigned long long*)(ws + off); off += (size_t)MAXLEN * B * 8;
  int* tokbuf               = (int*)(ws + off);                off += (size_t)32 * B * 4;
  float* hbuf               = (float*)(ws + off);              off += (size_t)2 * B * HID * 4;
  float* gi                 = (float*)(ws + off);              off += (size_t)B * G3 * 4;
  float* gh                 = (float*)(ws + off);              off += (size_t)B * G3 * 4;
  _Float16* h_hi            = (_Float16*)(ws + off);           off += (size_t)B * KP * 2;
  _Float16* h_lo            = (_Float16*)(ws + off);           off += (size_t)B * KP * 2;
  _Float16* w_hi            = (_Float16*)(ws + off);           off += (size_t)VPAD * KP * 2;
  _Float16* w_lo            = (_Float16*)(ws + off);           off += (size_t)VPAD * KP * 2;
  const size_t tier1_end = off;
  _Float16* wih_hi          = (_Float16*)(ws + off);           off += (size_t)MPAD * KIH * 2;
  _Float16* wih_lo          = (_Float16*)(ws + off);           off += (size_t)MPAD * KIH * 2;
  _Float16* whh_hi          = (_Float16*)(ws + off);           off += (size_t)MPAD * KP * 2;
  _Float16* whh_lo          = (_Float16*)(ws + off);           off += (size_t)MPAD * KP * 2;
  _Float16* x0_hi           = (_Float16*)(ws + off);           off += (size_t)B * KIH * 2;
  _Float16* x0_lo           = (_Float16*)(ws + off);           off += (size_t)B * KIH * 2;
  _Float16* xe_hi           = (_Float16*)(ws + off);           off += (size_t)B * KIH * 2;
  _Float16* xe_lo           = (_Float16*)(ws + off);           off += (size_t)B * KIH * 2;
  _Float16* xc_hi           = (_Float16*)(ws + off);           off += (size_t)B * KIH * 2;
  _Float16* xc_lo           = (_Float16*)(ws + off);           off += (size_t)B * KIH * 2;
  const size_t tier2_end = off;
  const int tier = (ws_size >= tier2_end) ? 2 : ((ws_size >= tier1_end) ? 1 : 0);

  k_init<<<(B * HID + 255) / 256, 256, 0, stream>>>(
      z, l, attr_w, emb_w, hbuf, keys, slots, tokbuf, y_out, h_hi, h_lo,
      x0_hi, x0_lo, xe_hi, xe_lo, (tier == 2) ? 1 : 0);

  if (tier >= 1) {
    int nthr4 = (int)(((size_t)VPAD * KP / 4 + 255) / 256);
    k_wsplit<<<nthr4, 256, 0, stream>>>(out_w, w_hi, w_lo);
  }
  if (tier == 2) {
    int tih = MPAD * KIH / 4, thh = MPAD * KP / 4;
    k_gwsplit<<<(tih + 255) / 256, 256, 0, stream>>>(W_ih, wih_hi, wih_lo, G3, EMB, KIH, tih);
    k_gwsplit<<<(thh + 255) / 256, 256, 0, stream>>>(W_hh, whh_hi, whh_lo, G3, HID, KP, thh);
  }

  for (int t = 0; t <= MAXLEN; ++t) {
    float* hprev = hbuf + (t % 2) * B * HID;
    float* hnext = hbuf + ((t + 1) % 2) * B * HID;

    if (tier == 2) {
      const _Float16* xh = (t == 0) ? x0_hi : ((t == MAXLEN) ? xe_hi : xc_hi);
      const _Float16* xl = (t == 0) ? x0_lo : ((t == MAXLEN) ? xe_lo : xc_lo);
      dim3 g2(33, 4, 2);
      k_gates2<<<g2, 256, 0, stream>>>(wih_hi, wih_lo, whh_hi, whh_lo,
                                       xh, xl, h_hi, h_lo, gi, gh);
    } else {
      const int* tok_t = tokbuf + ((t == MAXLEN) ? 31 : t) * B;
      dim3 ggrid(66, 8, 2);
      k_gates<<<ggrid, 256, 0, stream>>>(W_ih, W_hh, emb_w, hprev, tok_t, gi, gh);
    }
    k_hnew<<<(B * HID + 255) / 256, 256, 0, stream>>>(gi, gh, b_ih, b_hh, hprev,
                                                      hnext, hy, h_hi, h_lo, t);
    if (t < MAXLEN) {
      if (tier >= 1) {
        k_logits2<<<800, 256, 0, stream>>>(w_hi, w_lo, h_hi, h_lo, out_b, keys,
                                           slots + (size_t)t * B, t);
      } else {
        k_logits_f32<<<(VOCAB + 63) / 64, 256, 0, stream>>>(hnext, out_w, out_b, keys,
                                                            slots + (size_t)t * B, t);
      }
      k_tok2<<<B, 128, 0, stream>>>(slots + (size_t)t * B, emb_w,
                                    tokbuf + (t + 1) * B, y_out, xc_hi, xc_lo,
                                    t, (tier == 2) ? 1 : 0);
    }
  }
}

// Round 6
// 4025.036 us; speedup vs baseline: 10.5381x; 1.2253x over previous
//
#include <hip/hip_runtime.h>
#include <stdint.h>

#define VOCAB 50257
#define B 256
#define EMB 300
#define HID 700
#define G3 2100          // 3*HID
#define ZDIM 500
#define ATTR_EMBD 200
#define MAXLEN 30
#define SEQ 31           // MAXLEN+1
#define HY_ELEMS (B*SEQ*HID)
#define KP 704           // HID padded to mult of 32
#define NKT 22           // KP/32 k-tiles
#define KIH 320          // EMB padded to mult of 32
#define VPAD 50304       // VOCAB padded to mult of 128 (393*128)
#define NVT 393          // VPAD/128
#define MPAD 2112        // G3 padded to 33*64
#define SOS_IDX 1
#define EOS_IDX 2
// tiled chunk: per (tile, kt): [part(2)][4096 halves]; half idx = (kc*128+row)*8+e
#define CHUNK 4096
#define TILE_STRIDE ((size_t)NKT * 2 * CHUNK)   // halves per v-tile (or per h half-tile)

typedef _Float16 half8 __attribute__((ext_vector_type(8)));
typedef _Float16 half4 __attribute__((ext_vector_type(4)));
typedef float f32x4 __attribute__((ext_vector_type(4)));

// ---------------- global_load_lds helper (16B per lane, dest = wave base + lane*16)
typedef const __attribute__((address_space(1))) void* gas1_t;
typedef __attribute__((address_space(3))) void* las3_t;
__device__ __forceinline__ void gload_lds16(const void* g, void* l) {
  __builtin_amdgcn_global_load_lds((gas1_t)g, (las3_t)l, 16, 0, 0);
}

// ---------------- threefry2x32 (JAX-exact, 20 rounds) ----------------
__device__ __forceinline__ uint32_t rotl32(uint32_t x, int r) {
  return (x << r) | (x >> (32 - r));
}

__device__ __forceinline__ void threefry2x32(uint32_t k0, uint32_t k1,
                                             uint32_t x0, uint32_t x1,
                                             uint32_t& o0, uint32_t& o1) {
  const uint32_t ks2 = k0 ^ k1 ^ 0x1BD11BDAu;
  x0 += k0; x1 += k1;
#define TF_R4(a, b, c, d)                                     \
  x0 += x1; x1 = rotl32(x1, a); x1 ^= x0;                     \
  x0 += x1; x1 = rotl32(x1, b); x1 ^= x0;                     \
  x0 += x1; x1 = rotl32(x1, c); x1 ^= x0;                     \
  x0 += x1; x1 = rotl32(x1, d); x1 ^= x0;
  TF_R4(13, 15, 26, 6)  x0 += k1;  x1 += ks2 + 1u;
  TF_R4(17, 29, 16, 24) x0 += ks2; x1 += k0 + 2u;
  TF_R4(13, 15, 26, 6)  x0 += k0;  x1 += k1 + 3u;
  TF_R4(17, 29, 16, 24) x0 += k1;  x1 += ks2 + 4u;
  TF_R4(13, 15, 26, 6)  x0 += ks2; x1 += k0 + 5u;
#undef TF_R4
  o0 = x0; o1 = x1;
}

__device__ __forceinline__ unsigned long long gumbel_pack(float s, uint32_t key0,
                                                          uint32_t key1, int b, int v) {
  uint32_t j = (uint32_t)(b * VOCAB + v);
  uint32_t o0, o1;
  threefry2x32(key0, key1, 0u, j, o0, o1);
  uint32_t bits = o0 ^ o1;
  float f = __uint_as_float((bits >> 9) | 0x3f800000u) - 1.0f;
  float u = fmaxf(f, 1.17549435e-38f);
  float g = -logf(-logf(u));
  s += g;
  uint32_t us = __float_as_uint(s);
  us = (us & 0x80000000u) ? ~us : (us | 0x80000000u);
  return ((unsigned long long)us << 32) | (uint32_t)(~(uint32_t)v);
}

// split helper: val*scale -> {fp16 hi, fp16 lo=residual*2048}
struct hl16 { _Float16 hi, lo; };
__device__ __forceinline__ hl16 split16(float val, float scale) {
  float s = val * scale;
  _Float16 h = (_Float16)s;
  hl16 r;
  r.hi = h;
  r.lo = (_Float16)((s - (float)h) * 2048.0f);
  return r;
}

// ---------------- init ----------------
__global__ void k_init(const float* __restrict__ z, const int* __restrict__ l,
                       const float* __restrict__ attr_w, const float* __restrict__ emb_w,
                       float* __restrict__ hbuf0, uint32_t* __restrict__ keys,
                       unsigned long long* __restrict__ slots,
                       int* __restrict__ tok, float* __restrict__ y_out,
                       _Float16* __restrict__ h_hi, _Float16* __restrict__ h_lo,
                       _Float16* __restrict__ ht,
                       _Float16* __restrict__ x0_hi, _Float16* __restrict__ x0_lo,
                       _Float16* __restrict__ xe_hi, _Float16* __restrict__ xe_lo,
                       int full) {
  int idx = blockIdx.x * blockDim.x + threadIdx.x;
  if (idx < B * HID) {
    int b = idx / HID, i = idx % HID;
    float v = (i < ZDIM) ? z[b * ZDIM + i]
                         : attr_w[l[b] * ATTR_EMBD + (i - ZDIM)];
    hbuf0[idx] = v;
    hl16 r = split16(v, 8.0f);
    h_hi[b * KP + i] = r.hi;
    h_lo[b * KP + i] = r.lo;
  }
  if (idx < MAXLEN) {
    uint32_t o0, o1;
    threefry2x32(0u, 42u, 0u, (uint32_t)idx, o0, o1);
    keys[2 * idx] = o0; keys[2 * idx + 1] = o1;
  }
  if (idx < MAXLEN * B) slots[idx] = 0ull;
  if (idx < B) {
    tok[idx] = SOS_IDX;
    tok[31 * B + idx] = EOS_IDX;
    y_out[idx * SEQ + MAXLEN] = 2.0f;
  }
  if (idx < B * 4) {  // zero k-pad (700..703) of linear + tiled h
    int b = idx >> 2, k = HID + (idx & 3);
    h_hi[b * KP + k] = (_Float16)0.0f;
    h_lo[b * KP + k] = (_Float16)0.0f;
    int c = b >> 7, row = b & 127, e = k & 7;               // kt=21, kc=3
    size_t tb = (size_t)c * TILE_STRIDE + (size_t)21 * 2 * CHUNK
              + (3 * 128 + row) * 8 + e;
    ht[tb] = (_Float16)0.0f;
    ht[tb + CHUNK] = (_Float16)0.0f;
  }
  if (full && idx < KIH) {
    float v0 = (idx < EMB) ? emb_w[SOS_IDX * EMB + idx] : 0.0f;
    float ve = (idx < EMB) ? emb_w[EOS_IDX * EMB + idx] : 0.0f;
    hl16 r0 = split16(v0, 8.0f);
    hl16 re = split16(ve, 8.0f);
    for (int b = 0; b < B; ++b) {  // broadcast rows (all batches share SOS/EOS)
      x0_hi[b * KIH + idx] = r0.hi; x0_lo[b * KIH + idx] = r0.lo;
      xe_hi[b * KIH + idx] = re.hi; xe_lo[b * KIH + idx] = re.lo;
    }
  }
}

// ---------------- logits w split -> TILED LDS-image layout ----------------
// wt[p][kt][part][ (kc*128+row)*8+e ]; one thread handles one half4 of BOTH parts.
__global__ void k_wsplit(const float* __restrict__ out_w, _Float16* __restrict__ wt) {
  size_t idx = (size_t)blockIdx.x * blockDim.x + threadIdx.x;
  if (idx >= (size_t)NVT * NKT * 1024) return;
  int h4 = (int)(idx & 1023);
  int ktp = (int)(idx >> 10);
  int kt = ktp % NKT, p = ktp / NKT;
  int slot4 = h4 >> 1, e0 = (h4 & 1) * 4;
  int kc = slot4 >> 7, row = slot4 & 127;
  int v = p * 128 + row;
  int k = kt * 32 + kc * 8 + e0;
  float x[4];
  if (v < VOCAB && k + 3 < HID) {
    const float4 xv = *(const float4*)&out_w[(size_t)v * HID + k];
    x[0] = xv.x; x[1] = xv.y; x[2] = xv.z; x[3] = xv.w;
  } else {
#pragma unroll
    for (int j = 0; j < 4; ++j)
      x[j] = (v < VOCAB && k + j < HID) ? out_w[(size_t)v * HID + k + j] : 0.0f;
  }
  half4 hi, lo;
#pragma unroll
  for (int j = 0; j < 4; ++j) {
    hl16 r = split16(x[j], 64.0f);
    hi[j] = r.hi; lo[j] = r.lo;
  }
  size_t base = (size_t)p * TILE_STRIDE + (size_t)kt * 2 * CHUNK + slot4 * 8 + e0;
  *(half4*)&wt[base] = hi;
  *(half4*)&wt[base + CHUNK] = lo;
}

// ---------------- generic gate-weight split (Msrc x Ksrc -> MPAD x Kpad) ----------------
__global__ void k_gwsplit(const float* __restrict__ src, _Float16* __restrict__ hi,
                          _Float16* __restrict__ lo, int Msrc, int Ksrc, int Kpad,
                          int tot4) {
  int idx = blockIdx.x * blockDim.x + threadIdx.x;
  if (idx >= tot4) return;
  size_t i4 = (size_t)idx * 4;
  int m = (int)(i4 / Kpad), k = (int)(i4 % Kpad);
  half4 h, l;
#pragma unroll
  for (int j = 0; j < 4; ++j) {
    float x = (m < Msrc && k + j < Ksrc) ? src[(size_t)m * Ksrc + k + j] : 0.0f;
    hl16 r = split16(x, 64.0f);
    h[j] = r.hi; l[j] = r.lo;
  }
  *(half4*)&hi[i4] = h;
  *(half4*)&lo[i4] = l;
}

// ---------------- MFMA gates: 64j x 64b blocks, 4 waves (32x32), 2-phase gll+dbuf ----
__global__ __launch_bounds__(256, 4)
void k_gates2(const _Float16* __restrict__ wih_hi, const _Float16* __restrict__ wih_lo,
              const _Float16* __restrict__ whh_hi, const _Float16* __restrict__ whh_lo,
              const _Float16* __restrict__ x_hi, const _Float16* __restrict__ x_lo,
              const _Float16* __restrict__ h_hi, const _Float16* __restrict__ h_lo,
              float* __restrict__ gi, float* __restrict__ gh) {
  const int zz = blockIdx.z;
  const _Float16* __restrict__ Whi = zz ? whh_hi : wih_hi;
  const _Float16* __restrict__ Wlo = zz ? whh_lo : wih_lo;
  const _Float16* __restrict__ Xhi = zz ? h_hi : x_hi;
  const _Float16* __restrict__ Xlo = zz ? h_lo : x_lo;
  const int Kz = zz ? KP : KIH;
  float* __restrict__ out = zz ? gh : gi;

  const int jbase = blockIdx.x * 64;
  const int bbase = blockIdx.y * 64;
  __shared__ float4 lds[2][4][256];   // [buf][whi,wlo,xhi,xlo][kc*64+row]
  const int tid = threadIdx.x, lane = tid & 63, wid = tid >> 6;
  const int wj = wid >> 1, wb2 = wid & 1;
  const size_t wrow = (size_t)(jbase + lane) * Kz;   // stage: kc=wid, row=lane
  const size_t xrow = (size_t)(bbase + lane) * Kz;

  f32x4 acc_h[2][2], acc_x[2][2];
#pragma unroll
  for (int i = 0; i < 2; ++i)
#pragma unroll
    for (int j = 0; j < 2; ++j) { acc_h[i][j] = (f32x4)0.0f; acc_x[i][j] = (f32x4)0.0f; }

#define GSTAGE(bf, k0)                                                   \
  {                                                                      \
    gload_lds16(Whi + wrow + (k0) + wid * 8, &lds[bf][0][wid * 64]);     \
    gload_lds16(Wlo + wrow + (k0) + wid * 8, &lds[bf][1][wid * 64]);     \
    gload_lds16(Xhi + xrow + (k0) + wid * 8, &lds[bf][2][wid * 64]);     \
    gload_lds16(Xlo + xrow + (k0) + wid * 8, &lds[bf][3][wid * 64]);     \
  }

  const int nt = Kz / 32;
  GSTAGE(0, 0)
  for (int kt = 0; kt < nt; ++kt) {
    const int cur = kt & 1;
    __syncthreads();                       // drains staged loads for buf[cur]
    if (kt + 1 < nt) GSTAGE(cur ^ 1, (kt + 1) * 32)
    const int kcf = (lane >> 4) * 64 + (lane & 15);
    half8 a_hi[2], a_lo[2];
#pragma unroll
    for (int fv = 0; fv < 2; ++fv) {
      int s = kcf + wj * 32 + fv * 16;
      a_hi[fv] = *(const half8*)&lds[cur][0][s];
      a_lo[fv] = *(const half8*)&lds[cur][1][s];
    }
#pragma unroll
    for (int fb = 0; fb < 2; ++fb) {
      int s = kcf + wb2 * 32 + fb * 16;
      half8 b_hi = *(const half8*)&lds[cur][2][s];
      half8 b_lo = *(const half8*)&lds[cur][3][s];
#pragma unroll
      for (int fv = 0; fv < 2; ++fv) {
        acc_h[fv][fb] = __builtin_amdgcn_mfma_f32_16x16x32_f16(a_hi[fv], b_hi,
                                                               acc_h[fv][fb], 0, 0, 0);
        acc_x[fv][fb] = __builtin_amdgcn_mfma_f32_16x16x32_f16(a_hi[fv], b_lo,
                                                               acc_x[fv][fb], 0, 0, 0);
        acc_x[fv][fb] = __builtin_amdgcn_mfma_f32_16x16x32_f16(a_lo[fv], b_hi,
                                                               acc_x[fv][fb], 0, 0, 0);
      }
    }
  }
#undef GSTAGE

  const float c1 = 1.0f / 2048.0f, c2 = 1.0f / 512.0f;
#pragma unroll
  for (int fb = 0; fb < 2; ++fb) {
    const int b = bbase + wb2 * 32 + fb * 16 + (lane & 15);
#pragma unroll
    for (int fv = 0; fv < 2; ++fv) {
#pragma unroll
      for (int r = 0; r < 4; ++r) {
        int j = jbase + wj * 32 + fv * 16 + (lane >> 4) * 4 + r;
        if (j < G3)
          out[b * G3 + j] = (acc_h[fv][fb][r] + acc_x[fv][fb][r] * c1) * c2;
      }
    }
  }
}

// ---------------- fp32 gates fallback ----------------
__global__ void k_gates(const float* __restrict__ W_ih, const float* __restrict__ W_hh,
                        const float* __restrict__ emb_w, const float* __restrict__ hprev,
                        const int* __restrict__ tok,
                        float* __restrict__ gi, float* __restrict__ gh) {
  const int zz = blockIdx.z;
  const float* __restrict__ W = zz ? W_hh : W_ih;
  const int K = zz ? HID : EMB;
  float* __restrict__ out = zz ? gh : gi;
  __shared__ float w_lds[20][36];
  __shared__ float xh_lds[20][36];
  const int jbase = blockIdx.x * 32;
  const int bbase = blockIdx.y * 32;
  const int tid = threadIdx.x;
  const int tj = tid % 16, tb = tid / 16;
  float a00 = 0.f, a01 = 0.f, a10 = 0.f, a11 = 0.f;
  for (int k0 = 0; k0 < K; k0 += 20) {
    for (int idx = tid; idx < 640; idx += 256) {
      int col = idx / 20, kk = idx % 20;
      int j = jbase + col;
      w_lds[kk][col] = (j < G3) ? W[j * K + k0 + kk] : 0.0f;
      int b = bbase + col;
      float xv;
      if (zz) xv = hprev[b * HID + k0 + kk];
      else    xv = emb_w[tok[b] * EMB + k0 + kk];
      xh_lds[kk][col] = xv;
    }
    __syncthreads();
#pragma unroll
    for (int kk = 0; kk < 20; ++kk) {
      float w0 = w_lds[kk][tj * 2], w1 = w_lds[kk][tj * 2 + 1];
      float h0 = xh_lds[kk][tb * 2], h1 = xh_lds[kk][tb * 2 + 1];
      a00 += w0 * h0; a01 += w0 * h1;
      a10 += w1 * h0; a11 += w1 * h1;
    }
    __syncthreads();
  }
  int j0 = jbase + tj * 2, b0 = bbase + tb * 2;
  if (j0 < G3)     { out[b0 * G3 + j0] = a00;     out[(b0 + 1) * G3 + j0] = a01; }
  if (j0 + 1 < G3) { out[b0 * G3 + j0 + 1] = a10; out[(b0 + 1) * G3 + j0 + 1] = a11; }
}

// ---------------- pointwise GRU update + h fp16-split (linear for gates, tiled for logits)
__global__ void k_hnew(const float* __restrict__ gi, const float* __restrict__ gh,
                       const float* __restrict__ b_ih, const float* __restrict__ b_hh,
                       const float* __restrict__ hprev, float* __restrict__ hnext,
                       float* __restrict__ hy, _Float16* __restrict__ h_hi,
                       _Float16* __restrict__ h_lo, _Float16* __restrict__ ht, int t) {
  int idx = blockIdx.x * blockDim.x + threadIdx.x;
  if (idx >= B * HID) return;
  int b = idx / HID, i = idx % HID;
  float ir = gi[b * G3 + i]            + b_ih[i];
  float iz = gi[b * G3 + HID + i]      + b_ih[HID + i];
  float in_ = gi[b * G3 + 2 * HID + i] + b_ih[2 * HID + i];
  float hr = gh[b * G3 + i]            + b_hh[i];
  float hz = gh[b * G3 + HID + i]      + b_hh[HID + i];
  float hn = gh[b * G3 + 2 * HID + i]  + b_hh[2 * HID + i];
  float r  = 1.0f / (1.0f + expf(-(ir + hr)));
  float zg = 1.0f / (1.0f + expf(-(iz + hz)));
  float n  = tanhf(in_ + r * hn);
  float h  = (1.0f - zg) * n + zg * hprev[idx];
  hnext[idx] = h;
  hy[(size_t)b * SEQ * HID + (size_t)t * HID + i] = h;
  hl16 rr = split16(h, 8.0f);
  h_hi[b * KP + i] = rr.hi;
  h_lo[b * KP + i] = rr.lo;
  // tiled image for k_logits2: c=b>>7, row=b&127, kt=i>>5, kc=(i>>3)&3, e=i&7
  int c = b >> 7, row = b & 127;
  size_t tb = (size_t)c * TILE_STRIDE + (size_t)(i >> 5) * 2 * CHUNK
            + ((((i >> 3) & 3) * 128 + row) * 8) + (i & 7);
  ht[tb] = rr.hi;
  ht[tb + CHUNK] = rr.lo;
}

// ---------------- MFMA logits v3: tiled-image staging (contiguous 1KB gload_lds) ----
// grid: 800 flat blocks; xcd = bid&7 owns 50 v-tiles, pair (c=0/1) shares w-panel.
__global__ __launch_bounds__(256, 2)
void k_logits2(const _Float16* __restrict__ wt, const _Float16* __restrict__ ht,
               const float* __restrict__ out_b, const uint32_t* __restrict__ keys,
               unsigned long long* __restrict__ slot, int t) {
  const int bid = blockIdx.x;
  const int xcd = bid & 7, li = bid >> 3;
  const int p = xcd * 50 + (li >> 1);
  if (p >= NVT) return;
  const int c = li & 1;
  const int vbase = p * 128, bbase = c * 128;

  __shared__ float4 lds[2][4][512];   // [buf][whi,wlo,hhi,hlo][kc*128+row]
  const int tid = threadIdx.x;
  const int lane = tid & 63;
  const int wid = tid >> 6;
  const int wv = wid >> 1, wb = wid & 1;

  // staging: wave `wid` fills its whole 8KB array with 8 contiguous-1KB loads.
  // wid 0/1 -> w hi/lo ; wid 2/3 -> h hi/lo.
  const int part = wid & 1;
  const _Float16* tile_base = (wid < 2) ? (wt + (size_t)p * TILE_STRIDE)
                                        : (ht + (size_t)c * TILE_STRIDE);

  f32x4 acc_h[4][4];
  f32x4 acc_x[4][4];
#pragma unroll
  for (int i = 0; i < 4; ++i)
#pragma unroll
    for (int j = 0; j < 4; ++j) { acc_h[i][j] = (f32x4)0.0f; acc_x[i][j] = (f32x4)0.0f; }

#define LSTAGE(bf, kt)                                                          \
  {                                                                             \
    const _Float16* sb =                                                        \
        tile_base + ((size_t)(kt) * 2 + part) * CHUNK + lane * 8;               \
    _Pragma("unroll")                                                           \
    for (int i = 0; i < 8; ++i)                                                 \
      gload_lds16(sb + i * 512, &lds[bf][wid][i * 64]);                         \
  }

  LSTAGE(0, 0)
  for (int kt = 0; kt < NKT; ++kt) {
    const int cur = kt & 1;
    __syncthreads();                         // drains buf[cur]'s loads
    if (kt + 1 < NKT) LSTAGE(cur ^ 1, kt + 1)
    const int kcf = (lane >> 4) * 128 + (lane & 15);
    half8 a_hi[4], a_lo[4];
#pragma unroll
    for (int fv = 0; fv < 4; ++fv) {
      int s = kcf + wv * 64 + fv * 16;
      a_hi[fv] = *(const half8*)&lds[cur][0][s];
      a_lo[fv] = *(const half8*)&lds[cur][1][s];
    }
#pragma unroll
    for (int fb = 0; fb < 4; ++fb) {
      int s = kcf + wb * 64 + fb * 16;
      half8 b_hi = *(const half8*)&lds[cur][2][s];
      half8 b_lo = *(const half8*)&lds[cur][3][s];
#pragma unroll
      for (int fv = 0; fv < 4; ++fv) {
        acc_h[fv][fb] = __builtin_amdgcn_mfma_f32_16x16x32_f16(a_hi[fv], b_hi,
                                                               acc_h[fv][fb], 0, 0, 0);
        acc_x[fv][fb] = __builtin_amdgcn_mfma_f32_16x16x32_f16(a_hi[fv], b_lo,
                                                               acc_x[fv][fb], 0, 0, 0);
        acc_x[fv][fb] = __builtin_amdgcn_mfma_f32_16x16x32_f16(a_lo[fv], b_hi,
                                                               acc_x[fv][fb], 0, 0, 0);
      }
    }
  }
#undef LSTAGE

  const uint32_t key0 = keys[2 * t], key1 = keys[2 * t + 1];
  const float c1 = 1.0f / 2048.0f, c2 = 1.0f / 512.0f;
#pragma unroll
  for (int fb = 0; fb < 4; ++fb) {
    const int b = bbase + wb * 64 + fb * 16 + (lane & 15);
    unsigned long long best = 0ull;
#pragma unroll
    for (int fv = 0; fv < 4; ++fv) {
#pragma unroll
      for (int r = 0; r < 4; ++r) {
        int v = vbase + wv * 64 + fv * 16 + (lane >> 4) * 4 + r;
        if (v < VOCAB) {
          float s = (acc_h[fv][fb][r] + acc_x[fv][fb][r] * c1) * c2 + out_b[v];
          unsigned long long cand = gumbel_pack(s, key0, key1, b, v);
          if (cand > best) best = cand;
        }
      }
    }
    unsigned long long o;
    o = __shfl_xor(best, 16, 64); if (o > best) best = o;
    o = __shfl_xor(best, 32, 64); if (o > best) best = o;
    if ((lane >> 4) == 0) atomicMax(&slot[b], best);
  }
}

// ---------------- fp32 logits fallback ----------------
#define WPITCH 68
#define HPITCH 260
__global__ __launch_bounds__(256)
void k_logits_f32(const float* __restrict__ h, const float* __restrict__ out_w,
                  const float* __restrict__ out_b, const uint32_t* __restrict__ keys,
                  unsigned long long* __restrict__ slot, int t) {
  __shared__ float w_lds[20][WPITCH];
  __shared__ float h_lds[20][HPITCH];
  const int vbase = blockIdx.x * 64;
  const int tid = threadIdx.x;
  const int tv = tid % 8, tb = tid / 8;
  float acc[8][8];
#pragma unroll
  for (int i = 0; i < 8; ++i)
#pragma unroll
    for (int j = 0; j < 8; ++j) acc[i][j] = 0.f;

  for (int k0 = 0; k0 < HID; k0 += 20) {
    for (int idx = tid; idx < 64 * 20; idx += 256) {
      int vv = idx / 20, kk = idx % 20;
      int v = vbase + vv;
      w_lds[kk][vv] = (v < VOCAB) ? out_w[(size_t)v * HID + k0 + kk] : 0.0f;
    }
    for (int idx = tid; idx < 256 * 20; idx += 256) {
      int bb = idx / 20, kk = idx % 20;
      h_lds[kk][bb] = h[bb * HID + k0 + kk];
    }
    __syncthreads();
#pragma unroll
    for (int kk = 0; kk < 20; ++kk) {
      float wv[8], hv[8];
      *(float4*)&wv[0] = *(const float4*)&w_lds[kk][tv * 8];
      *(float4*)&wv[4] = *(const float4*)&w_lds[kk][tv * 8 + 4];
      *(float4*)&hv[0] = *(const float4*)&h_lds[kk][tb * 8];
      *(float4*)&hv[4] = *(const float4*)&h_lds[kk][tb * 8 + 4];
#pragma unroll
      for (int iv = 0; iv < 8; ++iv)
#pragma unroll
        for (int ib = 0; ib < 8; ++ib) acc[iv][ib] += wv[iv] * hv[ib];
    }
    __syncthreads();
  }

  const uint32_t key0 = keys[2 * t], key1 = keys[2 * t + 1];
#pragma unroll
  for (int ib = 0; ib < 8; ++ib) {
    const int b = tb * 8 + ib;
    unsigned long long best = 0ull;
#pragma unroll
    for (int iv = 0; iv < 8; ++iv) {
      int v = vbase + tv * 8 + iv;
      if (v >= VOCAB) continue;
      unsigned long long cand = gumbel_pack(acc[iv][ib] + out_b[v], key0, key1, b, v);
      if (cand > best) best = cand;
    }
#pragma unroll
    for (int off = 1; off < 8; off <<= 1) {
      unsigned long long other = __shfl_xor(best, off, 64);
      if (other > best) best = other;
    }
    if (tv == 0) atomicMax(&slot[b], best);
  }
}

// ---------------- token extraction + emb gather/split ----------------
__global__ void k_tok2(const unsigned long long* __restrict__ slot,
                       const float* __restrict__ emb_w,
                       int* __restrict__ tok_next, float* __restrict__ y_out,
                       _Float16* __restrict__ xc_hi, _Float16* __restrict__ xc_lo,
                       int t, int full) {
  const int b = blockIdx.x;
  const int c = threadIdx.x;   // 128 threads
  unsigned long long p = slot[b];
  uint32_t v = ~((uint32_t)(p & 0xFFFFFFFFull));
  if (c == 0) {
    tok_next[b] = (int)v;
    y_out[b * SEQ + t] = (float)v;
  }
  if (!full) return;
  if (c < 75) {
    float4 xv = *(const float4*)&emb_w[(size_t)v * EMB + c * 4];
    half4 hi, lo;
    hl16 r0 = split16(xv.x, 8.0f); hi[0] = r0.hi; lo[0] = r0.lo;
    hl16 r1 = split16(xv.y, 8.0f); hi[1] = r1.hi; lo[1] = r1.lo;
    hl16 r2 = split16(xv.z, 8.0f); hi[2] = r2.hi; lo[2] = r2.lo;
    hl16 r3 = split16(xv.w, 8.0f); hi[3] = r3.hi; lo[3] = r3.lo;
    *(half4*)&xc_hi[b * KIH + c * 4] = hi;
    *(half4*)&xc_lo[b * KIH + c * 4] = lo;
  } else if (c < 80) {
    *(half4*)&xc_hi[b * KIH + c * 4] = (half4)(_Float16)0.0f;
    *(half4*)&xc_lo[b * KIH + c * 4] = (half4)(_Float16)0.0f;
  }
}

// ---------------- host launch ----------------
extern "C" void kernel_launch(void* const* d_in, const int* in_sizes, int n_in,
                              void* d_out, int out_size, void* d_ws, size_t ws_size,
                              hipStream_t stream) {
  const float* z      = (const float*)d_in[0];
  const int*   l      = (const int*)  d_in[1];
  const float* emb_w  = (const float*)d_in[2];
  const float* attr_w = (const float*)d_in[3];
  const float* W_ih   = (const float*)d_in[4];
  const float* W_hh   = (const float*)d_in[5];
  const float* b_ih   = (const float*)d_in[6];
  const float* b_hh   = (const float*)d_in[7];
  const float* out_w  = (const float*)d_in[8];
  const float* out_b  = (const float*)d_in[9];

  float* hy    = (float*)d_out;
  float* y_out = (float*)d_out + HY_ELEMS;

  char* ws = (char*)d_ws;
  size_t off = 0;
  uint32_t* keys            = (uint32_t*)(ws + off);           off += 256;
  unsigned long long* slots = (unsigned long long*)(ws + off); off += (size_t)MAXLEN * B * 8;
  int* tokbuf               = (int*)(ws + off);                off += (size_t)32 * B * 4;
  float* hbuf               = (float*)(ws + off);              off += (size_t)2 * B * HID * 4;
  float* gi                 = (float*)(ws + off);              off += (size_t)B * G3 * 4;
  float* gh                 = (float*)(ws + off);              off += (size_t)B * G3 * 4;
  _Float16* h_hi            = (_Float16*)(ws + off);           off += (size_t)B * KP * 2;
  _Float16* h_lo            = (_Float16*)(ws + off);           off += (size_t)B * KP * 2;
  _Float16* ht              = (_Float16*)(ws + off);           off += (size_t)2 * TILE_STRIDE * 2;
  _Float16* wt              = (_Float16*)(ws + off);           off += (size_t)NVT * TILE_STRIDE * 2;
  const size_t tier1_end = off;
  _Float16* wih_hi          = (_Float16*)(ws + off);           off += (size_t)MPAD * KIH * 2;
  _Float16* wih_lo          = (_Float16*)(ws + off);           off += (size_t)MPAD * KIH * 2;
  _Float16* whh_hi          = (_Float16*)(ws + off);           off += (size_t)MPAD * KP * 2;
  _Float16* whh_lo          = (_Float16*)(ws + off);           off += (size_t)MPAD * KP * 2;
  _Float16* x0_hi           = (_Float16*)(ws + off);           off += (size_t)B * KIH * 2;
  _Float16* x0_lo           = (_Float16*)(ws + off);           off += (size_t)B * KIH * 2;
  _Float16* xe_hi           = (_Float16*)(ws + off);           off += (size_t)B * KIH * 2;
  _Float16* xe_lo           = (_Float16*)(ws + off);           off += (size_t)B * KIH * 2;
  _Float16* xc_hi           = (_Float16*)(ws + off);           off += (size_t)B * KIH * 2;
  _Float16* xc_lo           = (_Float16*)(ws + off);           off += (size_t)B * KIH * 2;
  const size_t tier2_end = off;
  const int tier = (ws_size >= tier2_end) ? 2 : ((ws_size >= tier1_end) ? 1 : 0);

  k_init<<<(B * HID + 255) / 256, 256, 0, stream>>>(
      z, l, attr_w, emb_w, hbuf, keys, slots, tokbuf, y_out, h_hi, h_lo, ht,
      x0_hi, x0_lo, xe_hi, xe_lo, (tier == 2) ? 1 : 0);

  if (tier >= 1) {
    size_t tot = (size_t)NVT * NKT * 1024;
    k_wsplit<<<(int)((tot + 255) / 256), 256, 0, stream>>>(out_w, wt);
  }
  if (tier == 2) {
    int tih = MPAD * KIH / 4, thh = MPAD * KP / 4;
    k_gwsplit<<<(tih + 255) / 256, 256, 0, stream>>>(W_ih, wih_hi, wih_lo, G3, EMB, KIH, tih);
    k_gwsplit<<<(thh + 255) / 256, 256, 0, stream>>>(W_hh, whh_hi, whh_lo, G3, HID, KP, thh);
  }

  for (int t = 0; t <= MAXLEN; ++t) {
    float* hprev = hbuf + (t % 2) * B * HID;
    float* hnext = hbuf + ((t + 1) % 2) * B * HID;

    if (tier == 2) {
      const _Float16* xh = (t == 0) ? x0_hi : ((t == MAXLEN) ? xe_hi : xc_hi);
      const _Float16* xl = (t == 0) ? x0_lo : ((t == MAXLEN) ? xe_lo : xc_lo);
      dim3 g2(33, 4, 2);
      k_gates2<<<g2, 256, 0, stream>>>(wih_hi, wih_lo, whh_hi, whh_lo,
                                       xh, xl, h_hi, h_lo, gi, gh);
    } else {
      const int* tok_t = tokbuf + ((t == MAXLEN) ? 31 : t) * B;
      dim3 ggrid(66, 8, 2);
      k_gates<<<ggrid, 256, 0, stream>>>(W_ih, W_hh, emb_w, hprev, tok_t, gi, gh);
    }
    k_hnew<<<(B * HID + 255) / 256, 256, 0, stream>>>(gi, gh, b_ih, b_hh, hprev,
                                                      hnext, hy, h_hi, h_lo, ht, t);
    if (t < MAXLEN) {
      if (tier >= 1) {
        k_logits2<<<800, 256, 0, stream>>>(wt, ht, out_b, keys,
                                           slots + (size_t)t * B, t);
      } else {
        k_logits_f32<<<(VOCAB + 63) / 64, 256, 0, stream>>>(hnext, out_w, out_b, keys,
                                                            slots + (size_t)t * B, t);
      }
      k_tok2<<<B, 128, 0, stream>>>(slots + (size_t)t * B, emb_w,
                                    tokbuf + (t + 1) * B, y_out, xc_hi, xc_lo,
                                    t, (tier == 2) ? 1 : 0);
    }
  }
}